// Round 1
// baseline (720.631 us; speedup 1.0000x reference)
//
#include <hip/hip_runtime.h>
#include <math.h>

#define B_  16
#define L_  4096
#define D_  64
#define R_  4
#define NB_ 64
#define BL_ 64

// ---------------- ws layout ----------------
// [0MB,1MB)   rmn    double [B][R][32][64]   normalized rand projections
// [1MB,2MB)   h      int    [B][R][L]        bucket id per position
// [2MB,3MB)   hi     int    [B][R][L]        sorted pos -> original l
// [3MB,4MB)   oi     int    [B][R][L]        original l -> sorted pos
// [4MB,5MB)   lse    float  [B][R][L]        (indexed by ORIGINAL l)
// [5MB,+256)  rwmax  float  [64]
// [5MB+256,)  rwsum  float  [64]
// [6MB,70MB)  attn   float  [B][R][L][64]    (indexed by ORIGINAL l)

// K0: normalize rand_matrix along d (axis=1), store as fp64 [b][r][n][d]
__global__ __launch_bounds__(64) void k_rmnorm(const float* __restrict__ rm,
                                               double* __restrict__ rmn) {
    int blk = blockIdx.x;                 // b*128 + r*32 + n
    int b = blk >> 7, r = (blk >> 5) & 3, n = blk & 31;
    int d = threadIdx.x;
    double v = (double)rm[(((size_t)b * 64 + d) * 4 + r) * 32 + n];
    double sq = v * v;
    #pragma unroll
    for (int off = 32; off > 0; off >>= 1) sq += __shfl_down(sq, off);
    double tot = __shfl(sq, 0);
    rmn[(((size_t)b * 4 + r) * 32 + n) * 64 + d] = v / sqrt(tot);
}

// K1: LSH hash. One thread per (b,l). fp64 dots so argmax matches exact math.
__global__ __launch_bounds__(256) void k_hash(const float* __restrict__ q,
                                              const double* __restrict__ rmn,
                                              int* __restrict__ h_ws) {
    __shared__ double rs[8192];          // [r][n][d] for this b, 64 KB
    int b = blockIdx.x >> 4;
    int l = ((blockIdx.x & 15) << 8) + threadIdx.x;
    for (int k = threadIdx.x; k < 8192; k += 256) rs[k] = rmn[(size_t)b * 8192 + k];
    __syncthreads();

    float qreg[64];
    const float4* qp = (const float4*)(q + ((size_t)b * L_ + l) * D_);
    #pragma unroll
    for (int c = 0; c < 16; c++) {
        float4 t = qp[c];
        qreg[4*c+0] = t.x; qreg[4*c+1] = t.y; qreg[4*c+2] = t.z; qreg[4*c+3] = t.w;
    }
    double ss = 0.0;
    #pragma unroll
    for (int d = 0; d < 64; d++) ss += (double)qreg[d] * (double)qreg[d];
    double nrm = sqrt(ss); if (nrm < 1e-12) nrm = 1e-12;
    double inv = 1.0 / nrm;

    for (int r = 0; r < 4; r++) {
        double bp = -1e300, bn = -1e300; int ip = 0, in2 = 0;
        for (int n = 0; n < 32; n++) {
            const double* rp = &rs[(r * 32 + n) * 64];
            double acc = 0.0;
            #pragma unroll
            for (int d = 0; d < 64; d++) acc += (double)qreg[d] * rp[d];
            acc *= inv;
            if (acc > bp)  { bp = acc;  ip = n; }   // first-occurrence wins
            if (-acc > bn) { bn = -acc; in2 = n; }
        }
        // concat([mm,-mm]): positives come first -> prefer positive on tie
        int idx = (bp >= bn) ? ip : (32 + in2);
        h_ws[((size_t)b * 4 + r) * L_ + l] = idx;
    }
}

// K2: stable counting sort of (bucket, position) per (b,r). Thread t owns bucket t.
__global__ __launch_bounds__(64) void k_sort(const int* __restrict__ h_ws,
                                             int* __restrict__ hi_ws,
                                             int* __restrict__ oi_ws) {
    __shared__ int hs[L_];
    __shared__ int cnt[64];
    int br = blockIdx.x;                  // b*4 + r
    const int* hp = h_ws + (size_t)br * L_;
    int t = threadIdx.x;
    for (int k = t; k < L_; k += 64) hs[k] = hp[k];
    __syncthreads();
    int c = 0;
    for (int k = 0; k < L_; k++) c += (hs[k] == t);
    cnt[t] = c;
    __syncthreads();
    int off = 0;
    for (int u = 0; u < t; u++) off += cnt[u];
    int* hi = hi_ws + (size_t)br * L_;
    int* oi = oi_ws + (size_t)br * L_;
    for (int k = 0; k < L_; k++) {
        if (hs[k] == t) { hi[off] = k; oi[k] = off; off++; }
    }
}

// K3: fused scores + masks + dup-count + softmax + PV per (b, bucket, round)
__global__ __launch_bounds__(256) void k_attn(const float* __restrict__ query,
                                              const float* __restrict__ value,
                                              const int* __restrict__ h_ws,
                                              const int* __restrict__ hi_ws,
                                              const int* __restrict__ oi_ws,
                                              float* __restrict__ lse_ws,
                                              float* __restrict__ attn_ws) {
    __shared__ float Kraw[128 * 68];      // raw query rows of window; reused as Sc[64*132]
    __shared__ float V[128 * 68];
    __shared__ float kinv[128];
    __shared__ int   kposs[128];
    __shared__ int   khh[128];
    __shared__ int   koi[128 * 4];        // sorted pos of key in every round
    __shared__ float lse_s[64];

    int idx = blockIdx.x;
    int b = idx >> 8, n = (idx >> 2) & 63, r = idx & 3;
    int tid = threadIdx.x;
    int hibase = (b * 4 + r) * L_;

    if (tid < 128) {
        int j = tid;
        int nprev = (n + 63) & 63;        // roll(x,1): window = bucket n-1 then n
        int spos = (j < 64) ? (nprev * 64 + j) : (n * 64 + (j - 64));
        int p = hi_ws[hibase + spos];
        kposs[j] = p;
        khh[j] = h_ws[hibase + p];
        #pragma unroll
        for (int r2 = 0; r2 < 4; r2++) koi[j * 4 + r2] = oi_ws[(b * 4 + r2) * L_ + p];
    }
    __syncthreads();
    {   // load rows: 2 threads per row, 32 floats each
        int j = tid >> 1, dh = (tid & 1) * 32;
        int p = kposs[j];
        const float4* qrow = (const float4*)(query + ((size_t)b * L_ + p) * 64 + dh);
        const float4* vrow = (const float4*)(value + ((size_t)b * L_ + p) * 64 + dh);
        float4* kd = (float4*)&Kraw[j * 68 + dh];
        float4* vd = (float4*)&V[j * 68 + dh];
        #pragma unroll
        for (int c2 = 0; c2 < 8; c2++) { kd[c2] = qrow[c2]; vd[c2] = vrow[c2]; }
    }
    __syncthreads();
    if (tid < 128) {
        int j = tid; double ss = 0.0;
        #pragma unroll
        for (int d = 0; d < 64; d++) { double v = (double)Kraw[j * 68 + d]; ss += v * v; }
        double nr = sqrt(ss); if (nr < 1e-12) nr = 1e-12;
        kinv[j] = (float)(1.0 / nr);
    }
    __syncthreads();

    // QK: thread = (ig, jg); i = ig*8+ii, j = jg+32*jj
    int ig = tid >> 5, jg = tid & 31;
    float acc[8][4];
    #pragma unroll
    for (int ii = 0; ii < 8; ii++)
        #pragma unroll
        for (int jj = 0; jj < 4; jj++) acc[ii][jj] = 0.f;

    for (int dc = 0; dc < 64; dc += 4) {
        float4 kv[4];
        #pragma unroll
        for (int jj = 0; jj < 4; jj++) kv[jj] = *(const float4*)&Kraw[(jg + 32 * jj) * 68 + dc];
        #pragma unroll
        for (int ii = 0; ii < 8; ii++) {
            float4 qv = *(const float4*)&Kraw[(64 + ig * 8 + ii) * 68 + dc];
            #pragma unroll
            for (int jj = 0; jj < 4; jj++)
                acc[ii][jj] += qv.x * kv[jj].x + qv.y * kv[jj].y + qv.z * kv[jj].z + qv.w * kv[jj].w;
        }
    }
    __syncthreads();                       // all QK reads of Kraw done
    float* Sc = Kraw;                      // overlay: 64*132 = 8448 <= 8704

    #pragma unroll
    for (int ii = 0; ii < 8; ii++) {
        #pragma unroll
        for (int jj = 0; jj < 4; jj++) {
            int i = ig * 8 + ii, j = jg + 32 * jj;
            float s = acc[ii][jj] * kinv[j] * 0.125f;
            int qp = kposs[64 + i], kp = kposs[j];
            if (khh[j] != khh[64 + i]) s = -1e9f;   // different hash bucket
            if (qp < kp) s = -1e9f;                 // causal
            if (qp == kp) s = -1e5f;                // self
            Sc[i * 132 + j] = s;
        }
    }
    __syncthreads();

    if (tid < 64) {                        // LSE per query row
        int i = tid;
        float m = -1e30f;
        for (int j = 0; j < 128; j++) m = fmaxf(m, Sc[i * 132 + j]);
        float sum = 0.f;
        for (int j = 0; j < 128; j++) sum += expf(Sc[i * 132 + j] - m);
        float lv = m + logf(sum);
        lse_s[i] = lv;
        lse_ws[hibase + kposs[64 + i]] = lv;   // store at ORIGINAL position
    }
    __syncthreads();

    // weights = exp(s - lse) / count   (count = #rounds whose window holds key)
    #pragma unroll
    for (int ii = 0; ii < 8; ii++) {
        #pragma unroll
        for (int jj = 0; jj < 4; jj++) {
            int i = ig * 8 + ii, j = jg + 32 * jj;
            float s = Sc[i * 132 + j];
            int c2 = 0;
            #pragma unroll
            for (int r2 = 0; r2 < 4; r2++) {
                int qb = koi[(64 + i) * 4 + r2] >> 6;
                int kb = koi[j * 4 + r2] >> 6;
                c2 += ((kb == qb) || (kb == ((qb + 63) & 63))) ? 1 : 0;
            }
            Sc[i * 132 + j] = expf(s - lse_s[i]) / (float)c2;
        }
    }
    __syncthreads();

    // PV: thread = (ig, dg); d in {dg, dg+32}
    int dg = tid & 31;
    float pacc[8][2];
    #pragma unroll
    for (int ii = 0; ii < 8; ii++) { pacc[ii][0] = 0.f; pacc[ii][1] = 0.f; }
    for (int j0 = 0; j0 < 128; j0 += 4) {
        float vj[4][2];
        #pragma unroll
        for (int jj = 0; jj < 4; jj++) {
            vj[jj][0] = V[(j0 + jj) * 68 + dg];
            vj[jj][1] = V[(j0 + jj) * 68 + dg + 32];
        }
        #pragma unroll
        for (int ii = 0; ii < 8; ii++) {
            float4 w4 = *(const float4*)&Sc[(ig * 8 + ii) * 132 + j0];
            pacc[ii][0] += w4.x * vj[0][0] + w4.y * vj[1][0] + w4.z * vj[2][0] + w4.w * vj[3][0];
            pacc[ii][1] += w4.x * vj[0][1] + w4.y * vj[1][1] + w4.z * vj[2][1] + w4.w * vj[3][1];
        }
    }
    #pragma unroll
    for (int ii = 0; ii < 8; ii++) {
        int i = ig * 8 + ii;
        size_t base = (((size_t)(b * 4 + r)) * L_ + kposs[64 + i]) * 64;
        attn_ws[base + dg]      = pacc[ii][0];
        attn_ws[base + dg + 32] = pacc[ii][1];
    }
}

// K4a: per (b,r) softmax-over-L stats of lse
__global__ __launch_bounds__(256) void k_rw(const float* __restrict__ lse_ws,
                                            float* __restrict__ rwmax,
                                            float* __restrict__ rwsum) {
    __shared__ float  red[256];
    __shared__ double redd[256];
    int br = blockIdx.x;
    const float* lp = lse_ws + (size_t)br * L_;
    int t = threadIdx.x;
    float m = -1e30f;
    for (int k = t; k < L_; k += 256) m = fmaxf(m, lp[k]);
    red[t] = m; __syncthreads();
    for (int s2 = 128; s2 > 0; s2 >>= 1) {
        if (t < s2) red[t] = fmaxf(red[t], red[t + s2]);
        __syncthreads();
    }
    float mm = red[0];
    double s = 0.0;
    for (int k = t; k < L_; k += 256) s += (double)expf(lp[k] - mm);
    redd[t] = s; __syncthreads();
    for (int s2 = 128; s2 > 0; s2 >>= 1) {
        if (t < s2) redd[t] += redd[t + s2];
        __syncthreads();
    }
    if (t == 0) { rwmax[br] = mm; rwsum[br] = (float)redd[0]; }
}

// K4b: out[b,l,d] = sum_r attn[b,r,l,d] * softmax_L(lse)[b,r,l]
__global__ __launch_bounds__(256) void k_out(const float* __restrict__ attn_ws,
                                             const float* __restrict__ lse_ws,
                                             const float* __restrict__ rwmax,
                                             const float* __restrict__ rwsum,
                                             float* __restrict__ out) {
    size_t gid = (size_t)blockIdx.x * 256 + threadIdx.x;   // B*L*64
    int d = (int)(gid & 63);
    size_t row = gid >> 6;                                  // b*L + l
    int b = (int)(row >> 12), l = (int)(row & 4095);
    float o = 0.f;
    #pragma unroll
    for (int r = 0; r < 4; r++) {
        int br = b * 4 + r;
        float w = expf(lse_ws[(size_t)br * L_ + l] - rwmax[br]) / rwsum[br];
        o += attn_ws[((size_t)br * L_ + l) * 64 + d] * w;
    }
    out[gid] = o;
}

extern "C" void kernel_launch(void* const* d_in, const int* in_sizes, int n_in,
                              void* d_out, int out_size, void* d_ws, size_t ws_size,
                              hipStream_t stream) {
    const float* query = (const float*)d_in[0];
    const float* value = (const float*)d_in[1];
    const float* rm    = (const float*)d_in[2];
    char* ws = (char*)d_ws;
    double* rmn    = (double*)ws;
    int*    h_ws   = (int*)(ws + ((size_t)1 << 20));
    int*    hi_ws  = (int*)(ws + ((size_t)2 << 20));
    int*    oi_ws  = (int*)(ws + ((size_t)3 << 20));
    float*  lse_ws = (float*)(ws + ((size_t)4 << 20));
    float*  rwmax  = (float*)(ws + ((size_t)5 << 20));
    float*  rwsum  = (float*)(ws + ((size_t)5 << 20) + 256);
    float*  attn_ws= (float*)(ws + ((size_t)6 << 20));
    float*  out    = (float*)d_out;

    hipLaunchKernelGGL(k_rmnorm, dim3(2048), dim3(64), 0, stream, rm, rmn);
    hipLaunchKernelGGL(k_hash,   dim3(256),  dim3(256), 0, stream, query, rmn, h_ws);
    hipLaunchKernelGGL(k_sort,   dim3(64),   dim3(64),  0, stream, h_ws, hi_ws, oi_ws);
    hipLaunchKernelGGL(k_attn,   dim3(4096), dim3(256), 0, stream,
                       query, value, h_ws, hi_ws, oi_ws, lse_ws, attn_ws);
    hipLaunchKernelGGL(k_rw,     dim3(64),   dim3(256), 0, stream, lse_ws, rwmax, rwsum);
    hipLaunchKernelGGL(k_out,    dim3(16384),dim3(256), 0, stream,
                       attn_ws, lse_ws, rwmax, rwsum, out);
}

// Round 2
// 334.477 us; speedup vs baseline: 2.1545x; 2.1545x over previous
//
#include <hip/hip_runtime.h>
#include <math.h>

#define B_  16
#define L_  4096
#define D_  64
#define R_  4
#define NB_ 64
#define BL_ 64

// ---------------- ws layout ----------------
// [0MB,1MB)   rmn    double [B][R][32][64]   normalized rand projections
// [1MB,2MB)   h      int    [B][R][L]        bucket id per position
// [2MB,3MB)   hi     int    [B][R][L]        sorted pos -> original l
// [3MB,4MB)   oi     int    [B][R][L]        original l -> sorted pos
// [4MB,5MB)   lse    float  [B][R][L]        (indexed by ORIGINAL l)
// [5MB,+256)  rwmax  float  [64]
// [5MB+256,)  rwsum  float  [64]
// [6MB,70MB)  attn   float  [B][R][L][64]    (indexed by ORIGINAL l)

// K0: normalize rand_matrix along d (axis=1), store as fp64 [b][r][n][d]
__global__ __launch_bounds__(64) void k_rmnorm(const float* __restrict__ rm,
                                               double* __restrict__ rmn) {
    int blk = blockIdx.x;                 // b*128 + r*32 + n
    int b = blk >> 7, r = (blk >> 5) & 3, n = blk & 31;
    int d = threadIdx.x;
    double v = (double)rm[(((size_t)b * 64 + d) * 4 + r) * 32 + n];
    double sq = v * v;
    #pragma unroll
    for (int off = 32; off > 0; off >>= 1) sq += __shfl_down(sq, off);
    double tot = __shfl(sq, 0);
    rmn[(((size_t)b * 4 + r) * 32 + n) * 64 + d] = v / sqrt(tot);
}

// K1: LSH hash. One block per (b, r, 256-l chunk); q unnormalized (argmax-invariant).
__global__ __launch_bounds__(256) void k_hash(const float* __restrict__ q,
                                              const double* __restrict__ rmn,
                                              int* __restrict__ h_ws) {
    __shared__ double rs[2048];           // [n][d] for this (b,r), 16 KB
    int blk = blockIdx.x;                 // b*64 + r*16 + chunk
    int b = blk >> 6, r = (blk >> 4) & 3, chunk = blk & 15;
    const double* src = rmn + ((size_t)(b * 4 + r)) * 2048;
    for (int k = threadIdx.x; k < 2048; k += 256) rs[k] = src[k];
    __syncthreads();

    int l = chunk * 256 + threadIdx.x;
    double qd[64];
    const float4* qp = (const float4*)(q + ((size_t)(b * L_ + l)) * D_);
    #pragma unroll
    for (int c = 0; c < 16; c++) {
        float4 t = qp[c];
        qd[4*c+0] = (double)t.x; qd[4*c+1] = (double)t.y;
        qd[4*c+2] = (double)t.z; qd[4*c+3] = (double)t.w;
    }
    double bp = -1e300, bn = -1e300; int ip = 0, in2 = 0;
    for (int n = 0; n < 32; n++) {
        const double* rp = &rs[n * 64];
        double acc = 0.0;
        #pragma unroll
        for (int d = 0; d < 64; d++) acc += qd[d] * rp[d];
        if (acc > bp)  { bp = acc;  ip = n; }    // first occurrence wins
        if (-acc > bn) { bn = -acc; in2 = n; }
    }
    int idx = (bp >= bn) ? ip : (32 + in2);      // positives first on tie
    h_ws[((size_t)(b * 4 + r)) * L_ + l] = idx;
}

// K2: stable counting sort per (b,r): 64 chunk-threads, chunked count + scan + place.
__global__ __launch_bounds__(64) void k_sort(const int* __restrict__ h_ws,
                                             int* __restrict__ hi_ws,
                                             int* __restrict__ oi_ws) {
    __shared__ int hs[64 * 65];           // padded [chunk][64]
    __shared__ int cnt[64 * 65];          // [chunk][bucket] -> running offsets
    int br = blockIdx.x;                  // b*4 + r
    const int* hp = h_ws + (size_t)br * L_;
    int t = threadIdx.x;
    for (int w = 0; w < 64; w++) hs[w * 65 + t] = hp[w * 64 + t];
    for (int u = 0; u < 64; u++) cnt[t * 65 + u] = 0;
    __syncthreads();
    for (int k = 0; k < 64; k++) {        // count own chunk
        int b2 = hs[t * 65 + k];
        cnt[t * 65 + b2]++;
    }
    __syncthreads();
    int cs = 0;                           // total count of bucket t
    for (int c = 0; c < 64; c++) cs += cnt[c * 65 + t];
    int v = cs;                           // exclusive scan over buckets (1 wave)
    #pragma unroll
    for (int off = 1; off < 64; off <<= 1) {
        int u = __shfl_up(v, off);
        if (t >= off) v += u;
    }
    int running = v - cs;                 // bucket base
    for (int c = 0; c < 64; c++) {        // per-chunk start offsets for bucket t
        int tmp = cnt[c * 65 + t];
        cnt[c * 65 + t] = running;
        running += tmp;
    }
    __syncthreads();
    int* hi = hi_ws + (size_t)br * L_;
    int* oi = oi_ws + (size_t)br * L_;
    for (int k = 0; k < 64; k++) {        // stable placement, chunk t in order
        int idx = t * 64 + k;
        int b2 = hs[t * 65 + k];
        int pos = cnt[t * 65 + b2]++;
        hi[pos] = idx;
        oi[idx] = pos;
    }
}

// K3: fused scores + masks + dup-count + softmax + PV per (b, chunk, round)
__global__ __launch_bounds__(256, 4) void k_attn(const float* __restrict__ query,
                                                 const float* __restrict__ value,
                                                 const int* __restrict__ h_ws,
                                                 const int* __restrict__ hi_ws,
                                                 const int* __restrict__ oi_ws,
                                                 float* __restrict__ lse_ws,
                                                 float* __restrict__ attn_ws) {
    __shared__ float Kraw[128 * 68];      // 34816 B; overlaid by Sc[64*132] after QK
    __shared__ float kinv[128];
    __shared__ int   kposs[128];
    __shared__ int   khh[128];
    __shared__ int   kbp_s[128];          // packed chunk-ids over 4 rounds (bytes)
    __shared__ int   qbm1_s[64];          // packed (chunk-1 mod 64)

    int idx = blockIdx.x;
    int b = idx >> 8, n = (idx >> 2) & 63, r = idx & 3;
    int tid = threadIdx.x;
    int hibase = (b * 4 + r) * L_;

    if (tid < 128) {
        int j = tid;
        int nprev = (n + 63) & 63;        // window = chunk n-1 then n
        int spos = (j < 64) ? (nprev * 64 + j) : (n * 64 + (j - 64));
        int p = hi_ws[hibase + spos];
        kposs[j] = p;
        khh[j] = h_ws[hibase + p];
        int pack = 0, packm1 = 0;
        #pragma unroll
        for (int r2 = 0; r2 < 4; r2++) {
            int bk = oi_ws[(b * 4 + r2) * L_ + p] >> 6;
            pack   |= bk << (8 * r2);
            packm1 |= ((bk + 63) & 63) << (8 * r2);
        }
        kbp_s[j] = pack;
        if (j >= 64) qbm1_s[j - 64] = packm1;
    }
    __syncthreads();
    {   // load K rows: 2 threads per row, 32 floats each
        int j = tid >> 1, dh = (tid & 1) * 32;
        int p = kposs[j];
        const float4* qrow = (const float4*)(query + ((size_t)(b * L_ + p)) * 64 + dh);
        float4* kd = (float4*)&Kraw[j * 68 + dh];
        #pragma unroll
        for (int c2 = 0; c2 < 8; c2++) kd[c2] = qrow[c2];
    }
    __syncthreads();
    if (tid < 128) {                      // key norms (fp64 accumulate, b128 reads)
        int j = tid;
        double ss = 0.0;
        const float4* kr = (const float4*)&Kraw[j * 68];
        #pragma unroll
        for (int c2 = 0; c2 < 16; c2++) {
            float4 t4 = kr[c2];
            ss += (double)t4.x * t4.x + (double)t4.y * t4.y
                + (double)t4.z * t4.z + (double)t4.w * t4.w;
        }
        double nr = sqrt(ss); if (nr < 1e-12) nr = 1e-12;
        kinv[j] = (float)(1.0 / nr);
    }
    __syncthreads();

    // QK: thread = (ig, jg); i = ig*8+ii, j = jg+32*jj
    int ig = tid >> 5, jg = tid & 31;
    float acc[8][4];
    #pragma unroll
    for (int ii = 0; ii < 8; ii++)
        #pragma unroll
        for (int jj = 0; jj < 4; jj++) acc[ii][jj] = 0.f;

    for (int dc = 0; dc < 64; dc += 4) {
        float4 kv[4];
        #pragma unroll
        for (int jj = 0; jj < 4; jj++) kv[jj] = *(const float4*)&Kraw[(jg + 32 * jj) * 68 + dc];
        #pragma unroll
        for (int ii = 0; ii < 8; ii++) {
            float4 qv = *(const float4*)&Kraw[(64 + ig * 8 + ii) * 68 + dc];
            #pragma unroll
            for (int jj = 0; jj < 4; jj++)
                acc[ii][jj] += qv.x * kv[jj].x + qv.y * kv[jj].y + qv.z * kv[jj].z + qv.w * kv[jj].w;
        }
    }
    // per-thread metadata (these LDS arrays are NOT overlaid)
    float ki[4]; int kp[4], kh[4], kb[4];
    #pragma unroll
    for (int jj = 0; jj < 4; jj++) {
        int j = jg + 32 * jj;
        ki[jj] = kinv[j]; kp[jj] = kposs[j]; kh[jj] = khh[j]; kb[jj] = kbp_s[j];
    }
    int qp[8], qh[8], qb[8], qm[8];
    #pragma unroll
    for (int ii = 0; ii < 8; ii++) {
        int i = ig * 8 + ii;
        qp[ii] = kposs[64 + i]; qh[ii] = khh[64 + i];
        qb[ii] = kbp_s[64 + i]; qm[ii] = qbm1_s[i];
    }
    __syncthreads();                      // QK reads of Kraw complete
    float* Sc = Kraw;                     // overlay: 64*132 = 8448 <= 8704

    float lse_r[8];
    #pragma unroll
    for (int ii = 0; ii < 8; ii++) {
        #pragma unroll
        for (int jj = 0; jj < 4; jj++) {
            float s = acc[ii][jj] * ki[jj] * 0.125f;
            if (kh[jj] != qh[ii]) s = -1e9f;       // different hash bucket
            if (qp[ii] < kp[jj])  s = -1e9f;       // causal
            if (qp[ii] == kp[jj]) s = -1e5f;       // self
            acc[ii][jj] = s;
        }
        // LSE across the 32 jg-lanes (xor 1..16 stays in the 32-lane half)
        float m = fmaxf(fmaxf(acc[ii][0], acc[ii][1]), fmaxf(acc[ii][2], acc[ii][3]));
        #pragma unroll
        for (int off = 1; off < 32; off <<= 1) m = fmaxf(m, __shfl_xor(m, off));
        float sum = expf(acc[ii][0] - m) + expf(acc[ii][1] - m)
                  + expf(acc[ii][2] - m) + expf(acc[ii][3] - m);
        #pragma unroll
        for (int off = 1; off < 32; off <<= 1) sum += __shfl_xor(sum, off);
        float lse = m + logf(sum);
        lse_r[ii] = lse;
        // dup-count via packed-byte compare (bytes <= 63, no carries)
        #pragma unroll
        for (int jj = 0; jj < 4; jj++) {
            int z1 = kb[jj] ^ qb[ii];
            int z2 = kb[jj] ^ qm[ii];
            int nz = __popc((z1 + 0x7f7f7f7f) & 0x80808080)
                   + __popc((z2 + 0x7f7f7f7f) & 0x80808080);
            float c2 = (float)(8 - nz);
            Sc[(ig * 8 + ii) * 132 + (jg + 32 * jj)] = expf(acc[ii][jj] - lse) / c2;
        }
    }
    if (jg == 0) {
        #pragma unroll
        for (int ii = 0; ii < 8; ii++) lse_ws[hibase + qp[ii]] = lse_r[ii];
    }
    __syncthreads();

    // PV: thread = (ig, dg); d in {dg, dg+32}; V re-read from global (L2-hot)
    int dg = tid & 31;
    const float* vbase = value + ((size_t)b * L_) * 64 + dg;
    float pacc[8][2];
    #pragma unroll
    for (int ii = 0; ii < 8; ii++) { pacc[ii][0] = 0.f; pacc[ii][1] = 0.f; }

    float nv0[4], nv1[4];
    #pragma unroll
    for (int jj = 0; jj < 4; jj++) {      // prefetch j0 = 0
        const float* vp = vbase + ((size_t)kposs[jj] << 6);
        nv0[jj] = vp[0]; nv1[jj] = vp[32];
    }
    for (int j0 = 0; j0 < 128; j0 += 4) {
        float cv0[4], cv1[4];
        #pragma unroll
        for (int jj = 0; jj < 4; jj++) { cv0[jj] = nv0[jj]; cv1[jj] = nv1[jj]; }
        if (j0 + 4 < 128) {
            #pragma unroll
            for (int jj = 0; jj < 4; jj++) {
                const float* vp = vbase + ((size_t)kposs[j0 + 4 + jj] << 6);
                nv0[jj] = vp[0]; nv1[jj] = vp[32];
            }
        }
        #pragma unroll
        for (int ii = 0; ii < 8; ii++) {
            const float4 w4 = *(const float4*)&Sc[(ig * 8 + ii) * 132 + j0];
            pacc[ii][0] += w4.x * cv0[0] + w4.y * cv0[1] + w4.z * cv0[2] + w4.w * cv0[3];
            pacc[ii][1] += w4.x * cv1[0] + w4.y * cv1[1] + w4.z * cv1[2] + w4.w * cv1[3];
        }
    }
    #pragma unroll
    for (int ii = 0; ii < 8; ii++) {
        size_t base = (((size_t)(b * 4 + r)) * L_ + qp[ii]) * 64;
        attn_ws[base + dg]      = pacc[ii][0];
        attn_ws[base + dg + 32] = pacc[ii][1];
    }
}

// K4a: per (b,r) softmax-over-L stats of lse
__global__ __launch_bounds__(256) void k_rw(const float* __restrict__ lse_ws,
                                            float* __restrict__ rwmax,
                                            float* __restrict__ rwsum) {
    __shared__ float  red[256];
    __shared__ double redd[256];
    int br = blockIdx.x;
    const float* lp = lse_ws + (size_t)br * L_;
    int t = threadIdx.x;
    float m = -1e30f;
    for (int k = t; k < L_; k += 256) m = fmaxf(m, lp[k]);
    red[t] = m; __syncthreads();
    for (int s2 = 128; s2 > 0; s2 >>= 1) {
        if (t < s2) red[t] = fmaxf(red[t], red[t + s2]);
        __syncthreads();
    }
    float mm = red[0];
    double s = 0.0;
    for (int k = t; k < L_; k += 256) s += (double)expf(lp[k] - mm);
    redd[t] = s; __syncthreads();
    for (int s2 = 128; s2 > 0; s2 >>= 1) {
        if (t < s2) redd[t] += redd[t + s2];
        __syncthreads();
    }
    if (t == 0) { rwmax[br] = mm; rwsum[br] = (float)redd[0]; }
}

// K4b: out[b,l,d] = sum_r attn[b,r,l,d] * softmax_L(lse)[b,r,l]
__global__ __launch_bounds__(256) void k_out(const float* __restrict__ attn_ws,
                                             const float* __restrict__ lse_ws,
                                             const float* __restrict__ rwmax,
                                             const float* __restrict__ rwsum,
                                             float* __restrict__ out) {
    size_t gid = (size_t)blockIdx.x * 256 + threadIdx.x;   // B*L*64
    int d = (int)(gid & 63);
    size_t row = gid >> 6;                                  // b*L + l
    int b = (int)(row >> 12), l = (int)(row & 4095);
    float o = 0.f;
    #pragma unroll
    for (int r = 0; r < 4; r++) {
        int br = b * 4 + r;
        float w = expf(lse_ws[(size_t)br * L_ + l] - rwmax[br]) / rwsum[br];
        o += attn_ws[((size_t)br * L_ + l) * 64 + d] * w;
    }
    out[gid] = o;
}

extern "C" void kernel_launch(void* const* d_in, const int* in_sizes, int n_in,
                              void* d_out, int out_size, void* d_ws, size_t ws_size,
                              hipStream_t stream) {
    const float* query = (const float*)d_in[0];
    const float* value = (const float*)d_in[1];
    const float* rm    = (const float*)d_in[2];
    char* ws = (char*)d_ws;
    double* rmn    = (double*)ws;
    int*    h_ws   = (int*)(ws + ((size_t)1 << 20));
    int*    hi_ws  = (int*)(ws + ((size_t)2 << 20));
    int*    oi_ws  = (int*)(ws + ((size_t)3 << 20));
    float*  lse_ws = (float*)(ws + ((size_t)4 << 20));
    float*  rwmax  = (float*)(ws + ((size_t)5 << 20));
    float*  rwsum  = (float*)(ws + ((size_t)5 << 20) + 256);
    float*  attn_ws= (float*)(ws + ((size_t)6 << 20));
    float*  out    = (float*)d_out;

    hipLaunchKernelGGL(k_rmnorm, dim3(2048), dim3(64),  0, stream, rm, rmn);
    hipLaunchKernelGGL(k_hash,   dim3(1024), dim3(256), 0, stream, query, rmn, h_ws);
    hipLaunchKernelGGL(k_sort,   dim3(64),   dim3(64),  0, stream, h_ws, hi_ws, oi_ws);
    hipLaunchKernelGGL(k_attn,   dim3(4096), dim3(256), 0, stream,
                       query, value, h_ws, hi_ws, oi_ws, lse_ws, attn_ws);
    hipLaunchKernelGGL(k_rw,     dim3(64),   dim3(256), 0, stream, lse_ws, rwmax, rwsum);
    hipLaunchKernelGGL(k_out,    dim3(16384),dim3(256), 0, stream,
                       attn_ws, lse_ws, rwmax, rwsum, out);
}

// Round 3
// 281.403 us; speedup vs baseline: 2.5609x; 1.1886x over previous
//
#include <hip/hip_runtime.h>
#include <math.h>

#define B_  16
#define L_  4096
#define D_  64
#define R_  4
#define NB_ 64
#define BL_ 64

typedef _Float16 f16x8 __attribute__((ext_vector_type(8)));
typedef float    f32x4 __attribute__((ext_vector_type(4)));

// ---------------- ws layout ----------------
// [0MB,1MB)   rmn    double [B][R][32][64]
// [1MB,2MB)   h      int    [B][R][L]
// [2MB,3MB)   hi     int    [B][R][L]
// [3MB,4MB)   oi     int    [B][R][L]
// [4MB,5MB)   lse    float  [B][R][L]   (original index)
// [5MB,+256)  rwmax  float  [64]
// [5MB+256,)  rwsum  float  [64]
// [6MB,70MB)  attn   float  [B][R][L][64]  (original index)

__global__ __launch_bounds__(64) void k_rmnorm(const float* __restrict__ rm,
                                               double* __restrict__ rmn) {
    int blk = blockIdx.x;                 // b*128 + r*32 + n
    int b = blk >> 7, r = (blk >> 5) & 3, n = blk & 31;
    int d = threadIdx.x;
    double v = (double)rm[(((size_t)b * 64 + d) * 4 + r) * 32 + n];
    double sq = v * v;
    #pragma unroll
    for (int off = 32; off > 0; off >>= 1) sq += __shfl_down(sq, off);
    double tot = __shfl(sq, 0);
    rmn[(((size_t)b * 4 + r) * 32 + n) * 64 + d] = v / sqrt(tot);
}

// K1: fp32 fast path; fp64 exact recheck when top-2 margin < 2e-3.
__global__ __launch_bounds__(256) void k_hash(const float* __restrict__ q,
                                              const double* __restrict__ rmn,
                                              int* __restrict__ h_ws) {
    __shared__ float rsf[2048];           // [n][d] fp32 copy, 8 KB
    int blk = blockIdx.x;                 // b*64 + r*16 + chunk
    int b = blk >> 6, r = (blk >> 4) & 3, chunk = blk & 15;
    const double* src = rmn + ((size_t)(b * 4 + r)) * 2048;
    for (int k = threadIdx.x; k < 2048; k += 256) rsf[k] = (float)src[k];
    __syncthreads();

    int l = chunk * 256 + threadIdx.x;
    float qf[64];
    const float4* qp = (const float4*)(q + ((size_t)(b * L_ + l)) * D_);
    #pragma unroll
    for (int c = 0; c < 16; c++) {
        float4 t = qp[c];
        qf[4*c+0] = t.x; qf[4*c+1] = t.y; qf[4*c+2] = t.z; qf[4*c+3] = t.w;
    }
    float v1 = -1e30f, v2 = -1e30f; int i1 = 0;
    for (int n = 0; n < 32; n++) {
        const float4* rp = (const float4*)&rsf[n * 64];
        float acc = 0.f;
        #pragma unroll
        for (int c = 0; c < 16; c++) {
            float4 t = rp[c];
            acc = fmaf(qf[4*c+0], t.x, acc); acc = fmaf(qf[4*c+1], t.y, acc);
            acc = fmaf(qf[4*c+2], t.z, acc); acc = fmaf(qf[4*c+3], t.w, acc);
        }
        if (acc > v1)      { v2 = v1; v1 = acc; i1 = n; }
        else if (acc > v2) { v2 = acc; }
        float na = -acc;
        if (na > v1)       { v2 = v1; v1 = na; i1 = 32 + n; }
        else if (na > v2)  { v2 = na; }
    }
    if (v1 - v2 < 2e-3f) {                // exact fp64 rescan, concat order
        double bv = -1e300; int bi = 0;
        for (int n = 0; n < 32; n++) {
            const double* rp = &src[n * 64];
            double acc = 0.0;
            for (int d = 0; d < 64; d++) acc += (double)qf[d] * rp[d];
            if (acc > bv) { bv = acc; bi = n; }
        }
        for (int n = 0; n < 32; n++) {
            const double* rp = &src[n * 64];
            double acc = 0.0;
            for (int d = 0; d < 64; d++) acc += (double)qf[d] * rp[d];
            if (-acc > bv) { bv = -acc; bi = 32 + n; }
        }
        i1 = bi;
    }
    h_ws[((size_t)(b * 4 + r)) * L_ + l] = i1;
}

// K2: stable counting sort per (b,r)
__global__ __launch_bounds__(64) void k_sort(const int* __restrict__ h_ws,
                                             int* __restrict__ hi_ws,
                                             int* __restrict__ oi_ws) {
    __shared__ int hs[64 * 65];
    __shared__ int cnt[64 * 65];
    int br = blockIdx.x;
    const int* hp = h_ws + (size_t)br * L_;
    int t = threadIdx.x;
    for (int w = 0; w < 64; w++) hs[w * 65 + t] = hp[w * 64 + t];
    for (int u = 0; u < 64; u++) cnt[t * 65 + u] = 0;
    __syncthreads();
    for (int k = 0; k < 64; k++) cnt[t * 65 + hs[t * 65 + k]]++;
    __syncthreads();
    int cs = 0;
    for (int c = 0; c < 64; c++) cs += cnt[c * 65 + t];
    int v = cs;
    #pragma unroll
    for (int off = 1; off < 64; off <<= 1) {
        int u = __shfl_up(v, off);
        if (t >= off) v += u;
    }
    int running = v - cs;
    for (int c = 0; c < 64; c++) {
        int tmp = cnt[c * 65 + t];
        cnt[c * 65 + t] = running;
        running += tmp;
    }
    __syncthreads();
    int* hi = hi_ws + (size_t)br * L_;
    int* oi = oi_ws + (size_t)br * L_;
    for (int k = 0; k < 64; k++) {
        int idx = t * 64 + k;
        int b2 = hs[t * 65 + k];
        int pos = cnt[t * 65 + b2]++;
        hi[pos] = idx;
        oi[idx] = pos;
    }
}

// K3: MFMA-based fused attention per (b, chunk, round).
// LDS region A: Kh[128][72] + Qh[64][72] halves; overlaid by Ph[64][136] after QK.
#define KQ_HALVES (128*72 + 64*72)
#define QOFF      (128*72)
__global__ __launch_bounds__(256, 3) void k_attn(const float* __restrict__ query,
                                                 const float* __restrict__ value,
                                                 const int* __restrict__ h_ws,
                                                 const int* __restrict__ hi_ws,
                                                 const int* __restrict__ oi_ws,
                                                 float* __restrict__ lse_ws,
                                                 float* __restrict__ attn_ws) {
    __shared__ _Float16 KQ[KQ_HALVES];    // 27648 B (Ph needs 17408 B)
    __shared__ _Float16 Vt[64 * 136];     // 17408 B, transposed V
    __shared__ int4 kmeta[128];           // (hash, pos, packed-bkt, 0)
    __shared__ int4 qmeta[64];            // (hash, pos, packed-bkt, packed-bkt-1)

    int idx = blockIdx.x;
    int b = idx >> 8, n = (idx >> 2) & 63, r = idx & 3;
    int tid = threadIdx.x;
    int w = tid >> 6, lane = tid & 63, quad = lane >> 4, l15 = lane & 15;
    int hibase = (b * 4 + r) * L_;

    if (tid < 128) {
        int j = tid;
        int nprev = (n + 63) & 63;
        int spos = (j < 64) ? (nprev * 64 + j) : (n * 64 + (j - 64));
        int p = hi_ws[hibase + spos];
        int hh = h_ws[hibase + p];
        int pack = 0, packm1 = 0;
        #pragma unroll
        for (int r2 = 0; r2 < 4; r2++) {
            int bk = oi_ws[(b * 4 + r2) * L_ + p] >> 6;
            pack   |= bk << (8 * r2);
            packm1 |= ((bk + 63) & 63) << (8 * r2);
        }
        kmeta[j] = make_int4(hh, p, pack, 0);
        if (j >= 64) qmeta[j - 64] = make_int4(hh, p, pack, packm1);
    }
    __syncthreads();

    {   // stage K (scaled f16), Q (f16), V^T (f16): 2 threads per row
        int j = tid >> 1, dh = (tid & 1) * 32;
        int p = kmeta[j].y;
        const float4* qrow = (const float4*)(query + ((size_t)(b * L_ + p)) * 64 + dh);
        const float4* vrow = (const float4*)(value + ((size_t)(b * L_ + p)) * 64 + dh);
        float qv[32];
        float ss = 0.f;
        #pragma unroll
        for (int c = 0; c < 8; c++) {
            float4 t = qrow[c];
            qv[4*c+0] = t.x; qv[4*c+1] = t.y; qv[4*c+2] = t.z; qv[4*c+3] = t.w;
            ss += t.x*t.x + t.y*t.y + t.z*t.z + t.w*t.w;
        }
        ss += __shfl_xor(ss, 1);
        float nr = sqrtf(ss); if (nr < 1e-12f) nr = 1e-12f;
        float kscale = 0.125f / nr;
        #pragma unroll
        for (int g = 0; g < 4; g++) {
            f16x8 hv;
            #pragma unroll
            for (int t2 = 0; t2 < 8; t2++) hv[t2] = (_Float16)(qv[g*8+t2] * kscale);
            *(f16x8*)&KQ[j * 72 + dh + g * 8] = hv;
        }
        if (j >= 64) {
            #pragma unroll
            for (int g = 0; g < 4; g++) {
                f16x8 hv;
                #pragma unroll
                for (int t2 = 0; t2 < 8; t2++) hv[t2] = (_Float16)qv[g*8+t2];
                *(f16x8*)&KQ[QOFF + (j - 64) * 72 + dh + g * 8] = hv;
            }
        }
        float vv[32];
        #pragma unroll
        for (int c = 0; c < 8; c++) {
            float4 t = vrow[c];
            vv[4*c+0] = t.x; vv[4*c+1] = t.y; vv[4*c+2] = t.z; vv[4*c+3] = t.w;
        }
        #pragma unroll
        for (int t2 = 0; t2 < 32; t2++) Vt[(dh + t2) * 136 + j] = (_Float16)vv[t2];
    }
    __syncthreads();

    // QK: wave w owns 16 q-rows [w*16, w*16+16); all 128 keys
    f32x4 acc[8];
    #pragma unroll
    for (int jt = 0; jt < 8; jt++) acc[jt] = (f32x4){0.f, 0.f, 0.f, 0.f};
    f16x8 afr[2];
    #pragma unroll
    for (int kt = 0; kt < 2; kt++)
        afr[kt] = *(const f16x8*)&KQ[QOFF + (w * 16 + l15) * 72 + kt * 32 + quad * 8];
    #pragma unroll
    for (int jt = 0; jt < 8; jt++) {
        #pragma unroll
        for (int kt = 0; kt < 2; kt++) {
            f16x8 bfr = *(const f16x8*)&KQ[(jt * 16 + l15) * 72 + kt * 32 + quad * 8];
            acc[jt] = __builtin_amdgcn_mfma_f32_16x16x32_f16(afr[kt], bfr, acc[jt], 0, 0, 0);
        }
    }

    // metadata into registers
    int4 qm4[4], km4[8];
    #pragma unroll
    for (int reg = 0; reg < 4; reg++) qm4[reg] = qmeta[w * 16 + quad * 4 + reg];
    #pragma unroll
    for (int jt = 0; jt < 8; jt++) km4[jt] = kmeta[jt * 16 + l15];
    __syncthreads();                      // all QK reads of KQ done -> overlay ok

    // masks + LSE + dup-count + P (f16) into Ph (overlay of KQ)
    float lse_r[4];
    #pragma unroll
    for (int reg = 0; reg < 4; reg++) {
        float s[8];
        #pragma unroll
        for (int jt = 0; jt < 8; jt++) {
            float v = acc[jt][reg];
            if (km4[jt].x != qm4[reg].x) v = -1e9f;   // different bucket
            if (qm4[reg].y < km4[jt].y)  v = -1e9f;   // causal
            if (qm4[reg].y == km4[jt].y) v = -1e5f;   // self
            s[jt] = v;
        }
        float m = s[0];
        #pragma unroll
        for (int jt = 1; jt < 8; jt++) m = fmaxf(m, s[jt]);
        #pragma unroll
        for (int off = 1; off < 16; off <<= 1) m = fmaxf(m, __shfl_xor(m, off));
        float sum = 0.f;
        #pragma unroll
        for (int jt = 0; jt < 8; jt++) sum += expf(s[jt] - m);
        #pragma unroll
        for (int off = 1; off < 16; off <<= 1) sum += __shfl_xor(sum, off);
        float lse = m + logf(sum);
        lse_r[reg] = lse;
        int i = w * 16 + quad * 4 + reg;
        #pragma unroll
        for (int jt = 0; jt < 8; jt++) {
            int z1 = km4[jt].z ^ qm4[reg].z;
            int z2 = km4[jt].z ^ qm4[reg].w;
            int nz = __popc((z1 + 0x7f7f7f7f) & 0x80808080)
                   + __popc((z2 + 0x7f7f7f7f) & 0x80808080);
            float c2 = (float)(8 - nz);
            float p = expf(s[jt] - lse) / c2;
            KQ[i * 136 + jt * 16 + l15] = (_Float16)p;   // Ph
        }
    }
    if (l15 == 0) {
        #pragma unroll
        for (int reg = 0; reg < 4; reg++)
            lse_ws[hibase + qm4[reg].y] = lse_r[reg];
    }
    __syncthreads();                      // Ph + (Vt already) visible

    // PV: O[64 q][64 d] = P[64][128] * V[128][64]
    f32x4 oacc[4];
    #pragma unroll
    for (int nt = 0; nt < 4; nt++) oacc[nt] = (f32x4){0.f, 0.f, 0.f, 0.f};
    #pragma unroll
    for (int kt = 0; kt < 4; kt++) {
        f16x8 pa = *(const f16x8*)&KQ[(w * 16 + l15) * 136 + kt * 32 + quad * 8];
        #pragma unroll
        for (int nt = 0; nt < 4; nt++) {
            f16x8 vb = *(const f16x8*)&Vt[(nt * 16 + l15) * 136 + kt * 32 + quad * 8];
            oacc[nt] = __builtin_amdgcn_mfma_f32_16x16x32_f16(pa, vb, oacc[nt], 0, 0, 0);
        }
    }
    #pragma unroll
    for (int reg = 0; reg < 4; reg++) {
        size_t base = (((size_t)(b * 4 + r)) * L_ + qm4[reg].y) * 64;
        #pragma unroll
        for (int nt = 0; nt < 4; nt++)
            attn_ws[base + nt * 16 + l15] = oacc[nt][reg];
    }
}

// K4a: per (b,r) softmax-over-L stats of lse
__global__ __launch_bounds__(256) void k_rw(const float* __restrict__ lse_ws,
                                            float* __restrict__ rwmax,
                                            float* __restrict__ rwsum) {
    __shared__ float  red[256];
    __shared__ double redd[256];
    int br = blockIdx.x;
    const float* lp = lse_ws + (size_t)br * L_;
    int t = threadIdx.x;
    float m = -1e30f;
    for (int k = t; k < L_; k += 256) m = fmaxf(m, lp[k]);
    red[t] = m; __syncthreads();
    for (int s2 = 128; s2 > 0; s2 >>= 1) {
        if (t < s2) red[t] = fmaxf(red[t], red[t + s2]);
        __syncthreads();
    }
    float mm = red[0];
    double s = 0.0;
    for (int k = t; k < L_; k += 256) s += (double)expf(lp[k] - mm);
    redd[t] = s; __syncthreads();
    for (int s2 = 128; s2 > 0; s2 >>= 1) {
        if (t < s2) redd[t] += redd[t + s2];
        __syncthreads();
    }
    if (t == 0) { rwmax[br] = mm; rwsum[br] = (float)redd[0]; }
}

// K4b: out[b,l,d] = sum_r attn[b,r,l,d] * softmax_L(lse)[b,r,l]
__global__ __launch_bounds__(256) void k_out(const float* __restrict__ attn_ws,
                                             const float* __restrict__ lse_ws,
                                             const float* __restrict__ rwmax,
                                             const float* __restrict__ rwsum,
                                             float* __restrict__ out) {
    size_t gid = (size_t)blockIdx.x * 256 + threadIdx.x;
    int d = (int)(gid & 63);
    size_t row = gid >> 6;
    int b = (int)(row >> 12), l = (int)(row & 4095);
    float o = 0.f;
    #pragma unroll
    for (int r = 0; r < 4; r++) {
        int br = b * 4 + r;
        float w = expf(lse_ws[(size_t)br * L_ + l] - rwmax[br]) / rwsum[br];
        o += attn_ws[((size_t)br * L_ + l) * 64 + d] * w;
    }
    out[gid] = o;
}

extern "C" void kernel_launch(void* const* d_in, const int* in_sizes, int n_in,
                              void* d_out, int out_size, void* d_ws, size_t ws_size,
                              hipStream_t stream) {
    const float* query = (const float*)d_in[0];
    const float* value = (const float*)d_in[1];
    const float* rm    = (const float*)d_in[2];
    char* ws = (char*)d_ws;
    double* rmn    = (double*)ws;
    int*    h_ws   = (int*)(ws + ((size_t)1 << 20));
    int*    hi_ws  = (int*)(ws + ((size_t)2 << 20));
    int*    oi_ws  = (int*)(ws + ((size_t)3 << 20));
    float*  lse_ws = (float*)(ws + ((size_t)4 << 20));
    float*  rwmax  = (float*)(ws + ((size_t)5 << 20));
    float*  rwsum  = (float*)(ws + ((size_t)5 << 20) + 256);
    float*  attn_ws= (float*)(ws + ((size_t)6 << 20));
    float*  out    = (float*)d_out;

    hipLaunchKernelGGL(k_rmnorm, dim3(2048), dim3(64),  0, stream, rm, rmn);
    hipLaunchKernelGGL(k_hash,   dim3(1024), dim3(256), 0, stream, query, rmn, h_ws);
    hipLaunchKernelGGL(k_sort,   dim3(64),   dim3(64),  0, stream, h_ws, hi_ws, oi_ws);
    hipLaunchKernelGGL(k_attn,   dim3(4096), dim3(256), 0, stream,
                       query, value, h_ws, hi_ws, oi_ws, lse_ws, attn_ws);
    hipLaunchKernelGGL(k_rw,     dim3(64),   dim3(256), 0, stream, lse_ws, rwmax, rwsum);
    hipLaunchKernelGGL(k_out,    dim3(16384),dim3(256), 0, stream,
                       attn_ws, lse_ws, rwmax, rwsum, out);
}

// Round 4
// 234.075 us; speedup vs baseline: 3.0786x; 1.2022x over previous
//
#include <hip/hip_runtime.h>
#include <math.h>

#define B_  16
#define L_  4096
#define D_  64
#define R_  4
#define NB_ 64
#define BL_ 64

typedef _Float16 f16x8 __attribute__((ext_vector_type(8)));
typedef float    f32x4 __attribute__((ext_vector_type(4)));

// ---------------- ws layout ----------------
// [0MB,1MB)   rmn    double [B][R][32][64]
// [1MB,2MB)   h      int    [B][R][L]
// [2MB,3MB)   hi     int    [B][R][L]
// [3MB,4MB)   oi     int    [B][R][L]
// [4MB,5MB)   lse    float  [B][R][L]   (original index)
// [5MB,+256)  rwmax  float  [64]
// [5MB+256,)  rwsum  float  [64]
// [6MB,70MB)  attn   float  [B][R][L][64]  (original index)

__global__ __launch_bounds__(64) void k_rmnorm(const float* __restrict__ rm,
                                               double* __restrict__ rmn) {
    int blk = blockIdx.x;                 // b*128 + r*32 + n
    int b = blk >> 7, r = (blk >> 5) & 3, n = blk & 31;
    int d = threadIdx.x;
    double v = (double)rm[(((size_t)b * 64 + d) * 4 + r) * 32 + n];
    double sq = v * v;
    #pragma unroll
    for (int off = 32; off > 0; off >>= 1) sq += __shfl_down(sq, off);
    double tot = __shfl(sq, 0);
    rmn[(((size_t)b * 4 + r) * 32 + n) * 64 + d] = v / sqrt(tot);
}

// K1: split-f16 MFMA hash. Block = (b, 64-q chunk); computes all 128 projections.
// dot = hi*hi + hi*lo + lo*hi in fp32 MFMA accumulators (err ~1e-6); fp64 exact
// rescan only when top-2 margin < 4e-5 (~1e-3 of rows).
__global__ __launch_bounds__(256, 4) void k_hash(const float* __restrict__ q,
                                                 const double* __restrict__ rmn,
                                                 int* __restrict__ h_ws) {
    __shared__ _Float16 Rhi[128 * 72];    // 18432 B
    __shared__ _Float16 Rlo[128 * 72];    // 18432 B
    int blk = blockIdx.x;                 // b*64 + chunk
    int b = blk >> 6, chunk = blk & 63;
    int tid = threadIdx.x;
    int w = tid >> 6, lane = tid & 63, quad = lane >> 4, l15 = lane & 15;

    {   // stage R: 128 rows (r*32+nn) x 64 d, split hi/lo
        int row = tid >> 1, dh = (tid & 1) * 32;
        const double* src = rmn + ((size_t)(b * 4 + (row >> 5))) * 2048 + (row & 31) * 64 + dh;
        #pragma unroll
        for (int g = 0; g < 4; g++) {
            f16x8 hv, lv;
            #pragma unroll
            for (int j = 0; j < 8; j++) {
                float f = (float)src[g * 8 + j];
                _Float16 hi = (_Float16)f;
                hv[j] = hi;
                lv[j] = (_Float16)(f - (float)hi);
            }
            *(f16x8*)&Rhi[row * 72 + dh + g * 8] = hv;
            *(f16x8*)&Rlo[row * 72 + dh + g * 8] = lv;
        }
    }

    // Q A-frags straight from global: row = chunk*64 + w*16 + l15
    int qrow = chunk * 64 + w * 16 + l15;
    const float* qp = q + ((size_t)(b * L_ + qrow)) * 64;
    f16x8 Ahi[2], Alo[2];
    #pragma unroll
    for (int kt = 0; kt < 2; kt++) {
        float4 t0 = *(const float4*)(qp + kt * 32 + quad * 8);
        float4 t1 = *(const float4*)(qp + kt * 32 + quad * 8 + 4);
        float fv[8] = {t0.x, t0.y, t0.z, t0.w, t1.x, t1.y, t1.z, t1.w};
        #pragma unroll
        for (int j = 0; j < 8; j++) {
            _Float16 hi = (_Float16)fv[j];
            Ahi[kt][j] = hi;
            Alo[kt][j] = (_Float16)(fv[j] - (float)hi);
        }
    }
    __syncthreads();

    f32x4 acc[8];
    #pragma unroll
    for (int jt = 0; jt < 8; jt++) acc[jt] = (f32x4){0.f, 0.f, 0.f, 0.f};
    #pragma unroll
    for (int jt = 0; jt < 8; jt++) {
        #pragma unroll
        for (int kt = 0; kt < 2; kt++) {
            f16x8 bh = *(const f16x8*)&Rhi[(jt * 16 + l15) * 72 + kt * 32 + quad * 8];
            f16x8 bl = *(const f16x8*)&Rlo[(jt * 16 + l15) * 72 + kt * 32 + quad * 8];
            acc[jt] = __builtin_amdgcn_mfma_f32_16x16x32_f16(Ahi[kt], bh, acc[jt], 0, 0, 0);
            acc[jt] = __builtin_amdgcn_mfma_f32_16x16x32_f16(Ahi[kt], bl, acc[jt], 0, 0, 0);
            acc[jt] = __builtin_amdgcn_mfma_f32_16x16x32_f16(Alo[kt], bh, acc[jt], 0, 0, 0);
        }
    }

    // argmax per (reg row, round) with first-occurrence concat([mm,-mm]) order
    #pragma unroll
    for (int r = 0; r < 4; r++) {
        #pragma unroll
        for (int reg = 0; reg < 4; reg++) {
            float va = acc[2 * r][reg];       // concat idx l15
            float vb = acc[2 * r + 1][reg];   // concat idx l15+16
            float v1 = va, v2 = -1e30f; int i1 = l15;
            if (vb > v1) { v2 = v1; v1 = vb; i1 = l15 + 16; } else v2 = vb;
            float c;
            c = -va;  // idx 32+l15
            if (c > v1) { v2 = v1; v1 = c; i1 = 32 + l15; } else if (c > v2) v2 = c;
            c = -vb;  // idx 48+l15
            if (c > v1) { v2 = v1; v1 = c; i1 = 48 + l15; } else if (c > v2) v2 = c;
            #pragma unroll
            for (int off = 1; off < 16; off <<= 1) {
                float ov1 = __shfl_xor(v1, off);
                int   oi1 = __shfl_xor(i1, off);
                float ov2 = __shfl_xor(v2, off);
                if (ov1 > v1 || (ov1 == v1 && oi1 < i1)) {
                    v2 = fmaxf(v1, ov2); v1 = ov1; i1 = oi1;
                } else {
                    v2 = fmaxf(v2, ov1);
                }
            }
            if (l15 == 0) {
                int l = chunk * 64 + w * 16 + quad * 4 + reg;
                if (v1 - v2 < 4e-5f) {        // exact fp64 rescan (rare)
                    const float* qr = q + ((size_t)(b * L_ + l)) * 64;
                    const double* src = rmn + ((size_t)(b * 4 + r)) * 2048;
                    double bp = -1e300, bn = -1e300; int ip = 0, in2 = 0;
                    for (int n = 0; n < 32; n++) {
                        const double* rp = &src[n * 64];
                        double a2 = 0.0;
                        for (int d = 0; d < 64; d++) a2 += (double)qr[d] * rp[d];
                        if (a2 > bp)  { bp = a2;  ip = n; }
                        if (-a2 > bn) { bn = -a2; in2 = n; }
                    }
                    i1 = (bp >= bn) ? ip : (32 + in2);
                }
                h_ws[((size_t)(b * 4 + r)) * L_ + l] = i1;
            }
        }
    }
}

// K2: stable counting sort per (b,r)
__global__ __launch_bounds__(64) void k_sort(const int* __restrict__ h_ws,
                                             int* __restrict__ hi_ws,
                                             int* __restrict__ oi_ws) {
    __shared__ int hs[64 * 65];
    __shared__ int cnt[64 * 65];
    int br = blockIdx.x;
    const int* hp = h_ws + (size_t)br * L_;
    int t = threadIdx.x;
    for (int w = 0; w < 64; w++) hs[w * 65 + t] = hp[w * 64 + t];
    for (int u = 0; u < 64; u++) cnt[t * 65 + u] = 0;
    __syncthreads();
    for (int k = 0; k < 64; k++) cnt[t * 65 + hs[t * 65 + k]]++;
    __syncthreads();
    int cs = 0;
    for (int c = 0; c < 64; c++) cs += cnt[c * 65 + t];
    int v = cs;
    #pragma unroll
    for (int off = 1; off < 64; off <<= 1) {
        int u = __shfl_up(v, off);
        if (t >= off) v += u;
    }
    int running = v - cs;
    for (int c = 0; c < 64; c++) {
        int tmp = cnt[c * 65 + t];
        cnt[c * 65 + t] = running;
        running += tmp;
    }
    __syncthreads();
    int* hi = hi_ws + (size_t)br * L_;
    int* oi = oi_ws + (size_t)br * L_;
    for (int k = 0; k < 64; k++) {
        int idx = t * 64 + k;
        int b2 = hs[t * 65 + k];
        int pos = cnt[t * 65 + b2]++;
        hi[pos] = idx;
        oi[idx] = pos;
    }
}

// K3: MFMA-based fused attention per (b, chunk, round).
#define KQ_HALVES (128*72 + 64*72)
#define QOFF      (128*72)
__global__ __launch_bounds__(256, 3) void k_attn(const float* __restrict__ query,
                                                 const float* __restrict__ value,
                                                 const int* __restrict__ h_ws,
                                                 const int* __restrict__ hi_ws,
                                                 const int* __restrict__ oi_ws,
                                                 float* __restrict__ lse_ws,
                                                 float* __restrict__ attn_ws) {
    __shared__ _Float16 KQ[KQ_HALVES];    // 27648 B (Ph overlay needs 17408 B)
    __shared__ _Float16 Vt[64 * 136];     // 17408 B
    __shared__ int4 kmeta[128];
    __shared__ int4 qmeta[64];

    int idx = blockIdx.x;
    int b = idx >> 8, n = (idx >> 2) & 63, r = idx & 3;
    int tid = threadIdx.x;
    int w = tid >> 6, lane = tid & 63, quad = lane >> 4, l15 = lane & 15;
    int hibase = (b * 4 + r) * L_;

    if (tid < 128) {
        int j = tid;
        int nprev = (n + 63) & 63;
        int spos = (j < 64) ? (nprev * 64 + j) : (n * 64 + (j - 64));
        int p = hi_ws[hibase + spos];
        int hh = h_ws[hibase + p];
        int pack = 0, packm1 = 0;
        #pragma unroll
        for (int r2 = 0; r2 < 4; r2++) {
            int bk = oi_ws[(b * 4 + r2) * L_ + p] >> 6;
            pack   |= bk << (8 * r2);
            packm1 |= ((bk + 63) & 63) << (8 * r2);
        }
        kmeta[j] = make_int4(hh, p, pack, 0);
        if (j >= 64) qmeta[j - 64] = make_int4(hh, p, pack, packm1);
    }
    __syncthreads();

    {   // stage K (scaled f16), Q (f16), V^T (f16): 2 threads per row
        int j = tid >> 1, dh = (tid & 1) * 32;
        int p = kmeta[j].y;
        const float4* qrow = (const float4*)(query + ((size_t)(b * L_ + p)) * 64 + dh);
        const float4* vrow = (const float4*)(value + ((size_t)(b * L_ + p)) * 64 + dh);
        float qv[32];
        float ss = 0.f;
        #pragma unroll
        for (int c = 0; c < 8; c++) {
            float4 t = qrow[c];
            qv[4*c+0] = t.x; qv[4*c+1] = t.y; qv[4*c+2] = t.z; qv[4*c+3] = t.w;
            ss += t.x*t.x + t.y*t.y + t.z*t.z + t.w*t.w;
        }
        ss += __shfl_xor(ss, 1);
        float nr = sqrtf(ss); if (nr < 1e-12f) nr = 1e-12f;
        float kscale = 0.125f / nr;
        #pragma unroll
        for (int g = 0; g < 4; g++) {
            f16x8 hv;
            #pragma unroll
            for (int t2 = 0; t2 < 8; t2++) hv[t2] = (_Float16)(qv[g*8+t2] * kscale);
            *(f16x8*)&KQ[j * 72 + dh + g * 8] = hv;
        }
        if (j >= 64) {
            #pragma unroll
            for (int g = 0; g < 4; g++) {
                f16x8 hv;
                #pragma unroll
                for (int t2 = 0; t2 < 8; t2++) hv[t2] = (_Float16)qv[g*8+t2];
                *(f16x8*)&KQ[QOFF + (j - 64) * 72 + dh + g * 8] = hv;
            }
        }
        float vv[32];
        #pragma unroll
        for (int c = 0; c < 8; c++) {
            float4 t = vrow[c];
            vv[4*c+0] = t.x; vv[4*c+1] = t.y; vv[4*c+2] = t.z; vv[4*c+3] = t.w;
        }
        #pragma unroll
        for (int t2 = 0; t2 < 32; t2++) Vt[(dh + t2) * 136 + j] = (_Float16)vv[t2];
    }
    __syncthreads();

    f32x4 acc[8];
    #pragma unroll
    for (int jt = 0; jt < 8; jt++) acc[jt] = (f32x4){0.f, 0.f, 0.f, 0.f};
    f16x8 afr[2];
    #pragma unroll
    for (int kt = 0; kt < 2; kt++)
        afr[kt] = *(const f16x8*)&KQ[QOFF + (w * 16 + l15) * 72 + kt * 32 + quad * 8];
    #pragma unroll
    for (int jt = 0; jt < 8; jt++) {
        #pragma unroll
        for (int kt = 0; kt < 2; kt++) {
            f16x8 bfr = *(const f16x8*)&KQ[(jt * 16 + l15) * 72 + kt * 32 + quad * 8];
            acc[jt] = __builtin_amdgcn_mfma_f32_16x16x32_f16(afr[kt], bfr, acc[jt], 0, 0, 0);
        }
    }

    int4 qm4[4], km4[8];
    #pragma unroll
    for (int reg = 0; reg < 4; reg++) qm4[reg] = qmeta[w * 16 + quad * 4 + reg];
    #pragma unroll
    for (int jt = 0; jt < 8; jt++) km4[jt] = kmeta[jt * 16 + l15];
    __syncthreads();

    float lse_r[4];
    #pragma unroll
    for (int reg = 0; reg < 4; reg++) {
        float s[8];
        #pragma unroll
        for (int jt = 0; jt < 8; jt++) {
            float v = acc[jt][reg];
            if (km4[jt].x != qm4[reg].x) v = -1e9f;
            if (qm4[reg].y < km4[jt].y)  v = -1e9f;
            if (qm4[reg].y == km4[jt].y) v = -1e5f;
            s[jt] = v;
        }
        float m = s[0];
        #pragma unroll
        for (int jt = 1; jt < 8; jt++) m = fmaxf(m, s[jt]);
        #pragma unroll
        for (int off = 1; off < 16; off <<= 1) m = fmaxf(m, __shfl_xor(m, off));
        float sum = 0.f;
        #pragma unroll
        for (int jt = 0; jt < 8; jt++) sum += expf(s[jt] - m);
        #pragma unroll
        for (int off = 1; off < 16; off <<= 1) sum += __shfl_xor(sum, off);
        float lse = m + logf(sum);
        lse_r[reg] = lse;
        int i = w * 16 + quad * 4 + reg;
        #pragma unroll
        for (int jt = 0; jt < 8; jt++) {
            int z1 = km4[jt].z ^ qm4[reg].z;
            int z2 = km4[jt].z ^ qm4[reg].w;
            int nz = __popc((z1 + 0x7f7f7f7f) & 0x80808080)
                   + __popc((z2 + 0x7f7f7f7f) & 0x80808080);
            float c2 = (float)(8 - nz);
            float p = expf(s[jt] - lse) / c2;
            KQ[i * 136 + jt * 16 + l15] = (_Float16)p;
        }
    }
    if (l15 == 0) {
        #pragma unroll
        for (int reg = 0; reg < 4; reg++)
            lse_ws[hibase + qm4[reg].y] = lse_r[reg];
    }
    __syncthreads();

    f32x4 oacc[4];
    #pragma unroll
    for (int nt = 0; nt < 4; nt++) oacc[nt] = (f32x4){0.f, 0.f, 0.f, 0.f};
    #pragma unroll
    for (int kt = 0; kt < 4; kt++) {
        f16x8 pa = *(const f16x8*)&KQ[(w * 16 + l15) * 136 + kt * 32 + quad * 8];
        #pragma unroll
        for (int nt = 0; nt < 4; nt++) {
            f16x8 vb = *(const f16x8*)&Vt[(nt * 16 + l15) * 136 + kt * 32 + quad * 8];
            oacc[nt] = __builtin_amdgcn_mfma_f32_16x16x32_f16(pa, vb, oacc[nt], 0, 0, 0);
        }
    }
    #pragma unroll
    for (int reg = 0; reg < 4; reg++) {
        size_t base = (((size_t)(b * 4 + r)) * L_ + qm4[reg].y) * 64;
        #pragma unroll
        for (int nt = 0; nt < 4; nt++)
            attn_ws[base + nt * 16 + l15] = oacc[nt][reg];
    }
}

// K4a: per (b,r) softmax-over-L stats of lse
__global__ __launch_bounds__(256) void k_rw(const float* __restrict__ lse_ws,
                                            float* __restrict__ rwmax,
                                            float* __restrict__ rwsum) {
    __shared__ float  red[256];
    __shared__ double redd[256];
    int br = blockIdx.x;
    const float* lp = lse_ws + (size_t)br * L_;
    int t = threadIdx.x;
    float m = -1e30f;
    for (int k = t; k < L_; k += 256) m = fmaxf(m, lp[k]);
    red[t] = m; __syncthreads();
    for (int s2 = 128; s2 > 0; s2 >>= 1) {
        if (t < s2) red[t] = fmaxf(red[t], red[t + s2]);
        __syncthreads();
    }
    float mm = red[0];
    double s = 0.0;
    for (int k = t; k < L_; k += 256) s += (double)expf(lp[k] - mm);
    redd[t] = s; __syncthreads();
    for (int s2 = 128; s2 > 0; s2 >>= 1) {
        if (t < s2) redd[t] += redd[t + s2];
        __syncthreads();
    }
    if (t == 0) { rwmax[br] = mm; rwsum[br] = (float)redd[0]; }
}

// K4b: out[b,l,d] = sum_r attn[b,r,l,d] * softmax_L(lse)[b,r,l]
__global__ __launch_bounds__(256) void k_out(const float* __restrict__ attn_ws,
                                             const float* __restrict__ lse_ws,
                                             const float* __restrict__ rwmax,
                                             const float* __restrict__ rwsum,
                                             float* __restrict__ out) {
    size_t gid = (size_t)blockIdx.x * 256 + threadIdx.x;
    int d = (int)(gid & 63);
    size_t row = gid >> 6;
    int b = (int)(row >> 12), l = (int)(row & 4095);
    float o = 0.f;
    #pragma unroll
    for (int r = 0; r < 4; r++) {
        int br = b * 4 + r;
        float w = expf(lse_ws[(size_t)br * L_ + l] - rwmax[br]) / rwsum[br];
        o += attn_ws[((size_t)br * L_ + l) * 64 + d] * w;
    }
    out[gid] = o;
}

extern "C" void kernel_launch(void* const* d_in, const int* in_sizes, int n_in,
                              void* d_out, int out_size, void* d_ws, size_t ws_size,
                              hipStream_t stream) {
    const float* query = (const float*)d_in[0];
    const float* value = (const float*)d_in[1];
    const float* rm    = (const float*)d_in[2];
    char* ws = (char*)d_ws;
    double* rmn    = (double*)ws;
    int*    h_ws   = (int*)(ws + ((size_t)1 << 20));
    int*    hi_ws  = (int*)(ws + ((size_t)2 << 20));
    int*    oi_ws  = (int*)(ws + ((size_t)3 << 20));
    float*  lse_ws = (float*)(ws + ((size_t)4 << 20));
    float*  rwmax  = (float*)(ws + ((size_t)5 << 20));
    float*  rwsum  = (float*)(ws + ((size_t)5 << 20) + 256);
    float*  attn_ws= (float*)(ws + ((size_t)6 << 20));
    float*  out    = (float*)d_out;

    hipLaunchKernelGGL(k_rmnorm, dim3(2048), dim3(64),  0, stream, rm, rmn);
    hipLaunchKernelGGL(k_hash,   dim3(1024), dim3(256), 0, stream, query, rmn, h_ws);
    hipLaunchKernelGGL(k_sort,   dim3(64),   dim3(64),  0, stream, h_ws, hi_ws, oi_ws);
    hipLaunchKernelGGL(k_attn,   dim3(4096), dim3(256), 0, stream,
                       query, value, h_ws, hi_ws, oi_ws, lse_ws, attn_ws);
    hipLaunchKernelGGL(k_rw,     dim3(64),   dim3(256), 0, stream, lse_ws, rwmax, rwsum);
    hipLaunchKernelGGL(k_out,    dim3(16384),dim3(256), 0, stream,
                       attn_ws, lse_ws, rwmax, rwsum, out);
}

// Round 5
// 228.322 us; speedup vs baseline: 3.1562x; 1.0252x over previous
//
#include <hip/hip_runtime.h>
#include <math.h>

#define B_  16
#define L_  4096
#define D_  64
#define R_  4
#define NB_ 64
#define BL_ 64

typedef _Float16 f16x8 __attribute__((ext_vector_type(8)));
typedef float    f32x4 __attribute__((ext_vector_type(4)));

// ---------------- ws layout ----------------
// [0MB,1MB)   rmn    double   [B][R][32][64]
// [1MB,2MB)   h      int      [B][R][L]
// [2MB,3MB)   hi     int      [B][R][L]
// [3MB,4MB)   oi     int      [B][R][L]
// [4MB,5MB)   lse    float    [B][R][L]   (original index)
// [5MB,+256)  rwmax  float    [64]
// [5MB+256,)  rwsum  float    [64]
// [6MB,40MB)  attn   _Float16 [B][R][L][64]  (original index)
// [40MB,+)    rhi    _Float16 [B][128][64]
// [41MB,+)    rlo    _Float16 [B][128][64]

// K0: normalize rand_matrix along d, store fp64 + split-f16 (hi/lo) copies.
__global__ __launch_bounds__(64) void k_rmnorm(const float* __restrict__ rm,
                                               double* __restrict__ rmn,
                                               _Float16* __restrict__ rhi_g,
                                               _Float16* __restrict__ rlo_g) {
    int blk = blockIdx.x;                 // b*128 + r*32 + n
    int b = blk >> 7, r = (blk >> 5) & 3, n = blk & 31;
    int d = threadIdx.x;
    double v = (double)rm[(((size_t)b * 64 + d) * 4 + r) * 32 + n];
    double sq = v * v;
    #pragma unroll
    for (int off = 32; off > 0; off >>= 1) sq += __shfl_down(sq, off);
    double tot = __shfl(sq, 0);
    double nv = v / sqrt(tot);
    rmn[(((size_t)b * 4 + r) * 32 + n) * 64 + d] = nv;
    float f = (float)nv;
    _Float16 hi = (_Float16)f;
    size_t gi = ((size_t)b * 128 + r * 32 + n) * 64 + d;
    rhi_g[gi] = hi;
    rlo_g[gi] = (_Float16)(f - (float)hi);
}

// K1: split-f16 MFMA hash; S transposed through LDS; per-thread serial argmax
// with exact reference tie semantics; rare per-thread fp64 rescan.
__global__ __launch_bounds__(256, 4) void k_hash(const float* __restrict__ q,
                                                 const double* __restrict__ rmn,
                                                 const _Float16* __restrict__ rhi_g,
                                                 const _Float16* __restrict__ rlo_g,
                                                 int* __restrict__ h_ws) {
    __shared__ __align__(16) char smem[36864];
    _Float16* Rhi = (_Float16*)smem;            // [128][72]
    _Float16* Rlo = (_Float16*)(smem + 18432);  // [128][72]
    float*    Sc  = (float*)smem;               // overlay [64][133] = 34048 B

    int blk = blockIdx.x;                 // b*64 + chunk
    int b = blk >> 6, chunk = blk & 63;
    int tid = threadIdx.x;
    int w = tid >> 6, lane = tid & 63, quad = lane >> 4, l15 = lane & 15;

    {   // stage R split halves: row = tid>>1, half dh
        int row = tid >> 1, dh = (tid & 1) * 32;
        const _Float16* sh = rhi_g + ((size_t)b * 128 + row) * 64 + dh;
        const _Float16* sl = rlo_g + ((size_t)b * 128 + row) * 64 + dh;
        #pragma unroll
        for (int g = 0; g < 4; g++) {
            *(f16x8*)&Rhi[row * 72 + dh + g * 8] = *(const f16x8*)(sh + g * 8);
            *(f16x8*)&Rlo[row * 72 + dh + g * 8] = *(const f16x8*)(sl + g * 8);
        }
    }

    // Q A-frags from global: row = chunk*64 + w*16 + l15
    int qrow = chunk * 64 + w * 16 + l15;
    const float* qp = q + ((size_t)(b * L_ + qrow)) * 64;
    f16x8 Ahi[2], Alo[2];
    #pragma unroll
    for (int kt = 0; kt < 2; kt++) {
        float4 t0 = *(const float4*)(qp + kt * 32 + quad * 8);
        float4 t1 = *(const float4*)(qp + kt * 32 + quad * 8 + 4);
        float fv[8] = {t0.x, t0.y, t0.z, t0.w, t1.x, t1.y, t1.z, t1.w};
        #pragma unroll
        for (int j = 0; j < 8; j++) {
            _Float16 hi = (_Float16)fv[j];
            Ahi[kt][j] = hi;
            Alo[kt][j] = (_Float16)(fv[j] - (float)hi);
        }
    }
    __syncthreads();

    f32x4 acc[8];
    #pragma unroll
    for (int jt = 0; jt < 8; jt++) acc[jt] = (f32x4){0.f, 0.f, 0.f, 0.f};
    #pragma unroll
    for (int jt = 0; jt < 8; jt++) {
        #pragma unroll
        for (int kt = 0; kt < 2; kt++) {
            f16x8 bh = *(const f16x8*)&Rhi[(jt * 16 + l15) * 72 + kt * 32 + quad * 8];
            f16x8 bl = *(const f16x8*)&Rlo[(jt * 16 + l15) * 72 + kt * 32 + quad * 8];
            acc[jt] = __builtin_amdgcn_mfma_f32_16x16x32_f16(Ahi[kt], bh, acc[jt], 0, 0, 0);
            acc[jt] = __builtin_amdgcn_mfma_f32_16x16x32_f16(Ahi[kt], bl, acc[jt], 0, 0, 0);
            acc[jt] = __builtin_amdgcn_mfma_f32_16x16x32_f16(Alo[kt], bh, acc[jt], 0, 0, 0);
        }
    }
    __syncthreads();                      // MFMA B-reads done -> overlay S

    // S[row][proj]: row = w*16 + quad*4 + reg, proj = jt*16 + l15, pad 133
    #pragma unroll
    for (int jt = 0; jt < 8; jt++) {
        #pragma unroll
        for (int reg = 0; reg < 4; reg++)
            Sc[(w * 16 + quad * 4 + reg) * 133 + jt * 16 + l15] = acc[jt][reg];
    }
    __syncthreads();

    // thread = (round r = tid>>6, row = tid&63): serial scan of 32 projections
    {
        int row = tid & 63, r = tid >> 6;
        const float* sp = &Sc[row * 133 + r * 32];
        float bp = -1e30f, bn = -1e30f; int ip = 0, in2 = 0;
        float v1 = -1e30f, v2 = -1e30f;
        #pragma unroll
        for (int n = 0; n < 32; n++) {
            float v = sp[n], nv = -v;
            if (v > bp)  { bp = v;  ip = n; }
            if (nv > bn) { bn = nv; in2 = n; }
            if (v > v1)       { v2 = v1; v1 = v; }
            else if (v > v2)  { v2 = v; }
            if (nv > v1)      { v2 = v1; v1 = nv; }
            else if (nv > v2) { v2 = nv; }
        }
        int i1 = (bp >= bn) ? ip : (32 + in2);   // positives first on tie
        int l = chunk * 64 + row;
        if (v1 - v2 < 4e-5f) {            // exact fp64 rescan (rare, per-thread)
            const float* qr = q + ((size_t)(b * L_ + l)) * 64;
            const double* src = rmn + ((size_t)(b * 4 + r)) * 2048;
            double bpd = -1e300, bnd = -1e300; int ipd = 0, ind = 0;
            for (int n = 0; n < 32; n++) {
                const double* rp = &src[n * 64];
                double a2 = 0.0;
                for (int d = 0; d < 64; d++) a2 += (double)qr[d] * rp[d];
                if (a2 > bpd)  { bpd = a2;  ipd = n; }
                if (-a2 > bnd) { bnd = -a2; ind = n; }
            }
            i1 = (bpd >= bnd) ? ipd : (32 + ind);
        }
        h_ws[((size_t)(b * 4 + r)) * L_ + l] = i1;
    }
}

// K2: stable counting sort per (b,r)
__global__ __launch_bounds__(64) void k_sort(const int* __restrict__ h_ws,
                                             int* __restrict__ hi_ws,
                                             int* __restrict__ oi_ws) {
    __shared__ int hs[64 * 65];
    __shared__ int cnt[64 * 65];
    int br = blockIdx.x;
    const int* hp = h_ws + (size_t)br * L_;
    int t = threadIdx.x;
    for (int w = 0; w < 64; w++) hs[w * 65 + t] = hp[w * 64 + t];
    for (int u = 0; u < 64; u++) cnt[t * 65 + u] = 0;
    __syncthreads();
    for (int k = 0; k < 64; k++) cnt[t * 65 + hs[t * 65 + k]]++;
    __syncthreads();
    int cs = 0;
    for (int c = 0; c < 64; c++) cs += cnt[c * 65 + t];
    int v = cs;
    #pragma unroll
    for (int off = 1; off < 64; off <<= 1) {
        int u = __shfl_up(v, off);
        if (t >= off) v += u;
    }
    int running = v - cs;
    for (int c = 0; c < 64; c++) {
        int tmp = cnt[c * 65 + t];
        cnt[c * 65 + t] = running;
        running += tmp;
    }
    __syncthreads();
    int* hi = hi_ws + (size_t)br * L_;
    int* oi = oi_ws + (size_t)br * L_;
    for (int k = 0; k < 64; k++) {
        int idx = t * 64 + k;
        int b2 = hs[t * 65 + k];
        int pos = cnt[t * 65 + b2]++;
        hi[pos] = idx;
        oi[idx] = pos;
    }
}

// K3: MFMA-based fused attention per (b, chunk, round). f16 attn output.
#define KQ_HALVES (128*72 + 64*72)
#define QOFF      (128*72)
__global__ __launch_bounds__(256, 3) void k_attn(const float* __restrict__ query,
                                                 const float* __restrict__ value,
                                                 const int* __restrict__ h_ws,
                                                 const int* __restrict__ hi_ws,
                                                 const int* __restrict__ oi_ws,
                                                 float* __restrict__ lse_ws,
                                                 _Float16* __restrict__ attn_ws) {
    __shared__ _Float16 KQ[KQ_HALVES];    // 27648 B (Ph overlay needs 17408 B)
    __shared__ _Float16 Vt[64 * 136];     // 17408 B
    __shared__ int4 kmeta[128];
    __shared__ int4 qmeta[64];

    int idx = blockIdx.x;
    int b = idx >> 8, n = (idx >> 2) & 63, r = idx & 3;
    int tid = threadIdx.x;
    int w = tid >> 6, lane = tid & 63, quad = lane >> 4, l15 = lane & 15;
    int hibase = (b * 4 + r) * L_;

    if (tid < 128) {
        int j = tid;
        int nprev = (n + 63) & 63;
        int spos = (j < 64) ? (nprev * 64 + j) : (n * 64 + (j - 64));
        int p = hi_ws[hibase + spos];
        int hh = h_ws[hibase + p];
        int pack = 0, packm1 = 0;
        #pragma unroll
        for (int r2 = 0; r2 < 4; r2++) {
            int bk = oi_ws[(b * 4 + r2) * L_ + p] >> 6;
            pack   |= bk << (8 * r2);
            packm1 |= ((bk + 63) & 63) << (8 * r2);
        }
        kmeta[j] = make_int4(hh, p, pack, 0);
        if (j >= 64) qmeta[j - 64] = make_int4(hh, p, pack, packm1);
    }
    __syncthreads();

    {   // stage K (scaled f16), Q (f16), V^T (f16): 2 threads per row
        int j = tid >> 1, dh = (tid & 1) * 32;
        int p = kmeta[j].y;
        const float4* qrow = (const float4*)(query + ((size_t)(b * L_ + p)) * 64 + dh);
        const float4* vrow = (const float4*)(value + ((size_t)(b * L_ + p)) * 64 + dh);
        float qv[32];
        float ss = 0.f;
        #pragma unroll
        for (int c = 0; c < 8; c++) {
            float4 t = qrow[c];
            qv[4*c+0] = t.x; qv[4*c+1] = t.y; qv[4*c+2] = t.z; qv[4*c+3] = t.w;
            ss += t.x*t.x + t.y*t.y + t.z*t.z + t.w*t.w;
        }
        ss += __shfl_xor(ss, 1);
        float nr = sqrtf(ss); if (nr < 1e-12f) nr = 1e-12f;
        float kscale = 0.125f / nr;
        #pragma unroll
        for (int g = 0; g < 4; g++) {
            f16x8 hv;
            #pragma unroll
            for (int t2 = 0; t2 < 8; t2++) hv[t2] = (_Float16)(qv[g*8+t2] * kscale);
            *(f16x8*)&KQ[j * 72 + dh + g * 8] = hv;
        }
        if (j >= 64) {
            #pragma unroll
            for (int g = 0; g < 4; g++) {
                f16x8 hv;
                #pragma unroll
                for (int t2 = 0; t2 < 8; t2++) hv[t2] = (_Float16)qv[g*8+t2];
                *(f16x8*)&KQ[QOFF + (j - 64) * 72 + dh + g * 8] = hv;
            }
        }
        float vv[32];
        #pragma unroll
        for (int c = 0; c < 8; c++) {
            float4 t = vrow[c];
            vv[4*c+0] = t.x; vv[4*c+1] = t.y; vv[4*c+2] = t.z; vv[4*c+3] = t.w;
        }
        #pragma unroll
        for (int t2 = 0; t2 < 32; t2++) Vt[(dh + t2) * 136 + j] = (_Float16)vv[t2];
    }
    __syncthreads();

    f32x4 acc[8];
    #pragma unroll
    for (int jt = 0; jt < 8; jt++) acc[jt] = (f32x4){0.f, 0.f, 0.f, 0.f};
    f16x8 afr[2];
    #pragma unroll
    for (int kt = 0; kt < 2; kt++)
        afr[kt] = *(const f16x8*)&KQ[QOFF + (w * 16 + l15) * 72 + kt * 32 + quad * 8];
    #pragma unroll
    for (int jt = 0; jt < 8; jt++) {
        #pragma unroll
        for (int kt = 0; kt < 2; kt++) {
            f16x8 bfr = *(const f16x8*)&KQ[(jt * 16 + l15) * 72 + kt * 32 + quad * 8];
            acc[jt] = __builtin_amdgcn_mfma_f32_16x16x32_f16(afr[kt], bfr, acc[jt], 0, 0, 0);
        }
    }

    int4 qm4[4], km4[8];
    #pragma unroll
    for (int reg = 0; reg < 4; reg++) qm4[reg] = qmeta[w * 16 + quad * 4 + reg];
    #pragma unroll
    for (int jt = 0; jt < 8; jt++) km4[jt] = kmeta[jt * 16 + l15];
    __syncthreads();

    float lse_r[4];
    #pragma unroll
    for (int reg = 0; reg < 4; reg++) {
        float s[8];
        #pragma unroll
        for (int jt = 0; jt < 8; jt++) {
            float v = acc[jt][reg];
            if (km4[jt].x != qm4[reg].x) v = -1e9f;
            if (qm4[reg].y < km4[jt].y)  v = -1e9f;
            if (qm4[reg].y == km4[jt].y) v = -1e5f;
            s[jt] = v;
        }
        float m = s[0];
        #pragma unroll
        for (int jt = 1; jt < 8; jt++) m = fmaxf(m, s[jt]);
        #pragma unroll
        for (int off = 1; off < 16; off <<= 1) m = fmaxf(m, __shfl_xor(m, off));
        float te[8], sum = 0.f;
        #pragma unroll
        for (int jt = 0; jt < 8; jt++) { te[jt] = __expf(s[jt] - m); sum += te[jt]; }
        #pragma unroll
        for (int off = 1; off < 16; off <<= 1) sum += __shfl_xor(sum, off);
        float inv = 1.f / sum;
        lse_r[reg] = m + __logf(sum);
        int i = w * 16 + quad * 4 + reg;
        #pragma unroll
        for (int jt = 0; jt < 8; jt++) {
            int z1 = km4[jt].z ^ qm4[reg].z;
            int z2 = km4[jt].z ^ qm4[reg].w;
            int nz = __popc((z1 + 0x7f7f7f7f) & 0x80808080)
                   + __popc((z2 + 0x7f7f7f7f) & 0x80808080);
            float p = te[jt] * inv / (float)(8 - nz);
            KQ[i * 136 + jt * 16 + l15] = (_Float16)p;
        }
    }
    if (l15 == 0) {
        #pragma unroll
        for (int reg = 0; reg < 4; reg++)
            lse_ws[hibase + qm4[reg].y] = lse_r[reg];
    }
    __syncthreads();

    f32x4 oacc[4];
    #pragma unroll
    for (int nt = 0; nt < 4; nt++) oacc[nt] = (f32x4){0.f, 0.f, 0.f, 0.f};
    #pragma unroll
    for (int kt = 0; kt < 4; kt++) {
        f16x8 pa = *(const f16x8*)&KQ[(w * 16 + l15) * 136 + kt * 32 + quad * 8];
        #pragma unroll
        for (int nt = 0; nt < 4; nt++) {
            f16x8 vb = *(const f16x8*)&Vt[(nt * 16 + l15) * 136 + kt * 32 + quad * 8];
            oacc[nt] = __builtin_amdgcn_mfma_f32_16x16x32_f16(pa, vb, oacc[nt], 0, 0, 0);
        }
    }
    #pragma unroll
    for (int reg = 0; reg < 4; reg++) {
        size_t base = (((size_t)(b * 4 + r)) * L_ + qm4[reg].y) * 64;
        #pragma unroll
        for (int nt = 0; nt < 4; nt++)
            attn_ws[base + nt * 16 + l15] = (_Float16)oacc[nt][reg];
    }
}

// K4a: per (b,r) softmax-over-L stats of lse
__global__ __launch_bounds__(256) void k_rw(const float* __restrict__ lse_ws,
                                            float* __restrict__ rwmax,
                                            float* __restrict__ rwsum) {
    __shared__ float  red[256];
    __shared__ double redd[256];
    int br = blockIdx.x;
    const float* lp = lse_ws + (size_t)br * L_;
    int t = threadIdx.x;
    float m = -1e30f;
    for (int k = t; k < L_; k += 256) m = fmaxf(m, lp[k]);
    red[t] = m; __syncthreads();
    for (int s2 = 128; s2 > 0; s2 >>= 1) {
        if (t < s2) red[t] = fmaxf(red[t], red[t + s2]);
        __syncthreads();
    }
    float mm = red[0];
    double s = 0.0;
    for (int k = t; k < L_; k += 256) s += (double)expf(lp[k] - mm);
    redd[t] = s; __syncthreads();
    for (int s2 = 128; s2 > 0; s2 >>= 1) {
        if (t < s2) redd[t] += redd[t + s2];
        __syncthreads();
    }
    if (t == 0) { rwmax[br] = mm; rwsum[br] = (float)redd[0]; }
}

// K4b: out[b,l,d] = sum_r attn[b,r,l,d] * softmax_L(lse)[b,r,l]
__global__ __launch_bounds__(256) void k_out(const _Float16* __restrict__ attn_ws,
                                             const float* __restrict__ lse_ws,
                                             const float* __restrict__ rwmax,
                                             const float* __restrict__ rwsum,
                                             float* __restrict__ out) {
    size_t gid = (size_t)blockIdx.x * 256 + threadIdx.x;
    int d = (int)(gid & 63);
    size_t row = gid >> 6;
    int b = (int)(row >> 12), l = (int)(row & 4095);
    float o = 0.f;
    #pragma unroll
    for (int r = 0; r < 4; r++) {
        int br = b * 4 + r;
        float w = expf(lse_ws[(size_t)br * L_ + l] - rwmax[br]) / rwsum[br];
        o += (float)attn_ws[(((size_t)br * L_ + l) << 6) + d] * w;
    }
    out[gid] = o;
}

extern "C" void kernel_launch(void* const* d_in, const int* in_sizes, int n_in,
                              void* d_out, int out_size, void* d_ws, size_t ws_size,
                              hipStream_t stream) {
    const float* query = (const float*)d_in[0];
    const float* value = (const float*)d_in[1];
    const float* rm    = (const float*)d_in[2];
    char* ws = (char*)d_ws;
    double*    rmn    = (double*)ws;
    int*       h_ws   = (int*)(ws + ((size_t)1 << 20));
    int*       hi_ws  = (int*)(ws + ((size_t)2 << 20));
    int*       oi_ws  = (int*)(ws + ((size_t)3 << 20));
    float*     lse_ws = (float*)(ws + ((size_t)4 << 20));
    float*     rwmax  = (float*)(ws + ((size_t)5 << 20));
    float*     rwsum  = (float*)(ws + ((size_t)5 << 20) + 256);
    _Float16*  attn_ws= (_Float16*)(ws + ((size_t)6 << 20));
    _Float16*  rhi_g  = (_Float16*)(ws + ((size_t)40 << 20));
    _Float16*  rlo_g  = (_Float16*)(ws + ((size_t)41 << 20));
    float*     out    = (float*)d_out;

    hipLaunchKernelGGL(k_rmnorm, dim3(2048), dim3(64),  0, stream, rm, rmn, rhi_g, rlo_g);
    hipLaunchKernelGGL(k_hash,   dim3(1024), dim3(256), 0, stream, query, rmn, rhi_g, rlo_g, h_ws);
    hipLaunchKernelGGL(k_sort,   dim3(64),   dim3(64),  0, stream, h_ws, hi_ws, oi_ws);
    hipLaunchKernelGGL(k_attn,   dim3(4096), dim3(256), 0, stream,
                       query, value, h_ws, hi_ws, oi_ws, lse_ws, attn_ws);
    hipLaunchKernelGGL(k_rw,     dim3(64),   dim3(256), 0, stream, lse_ws, rwmax, rwsum);
    hipLaunchKernelGGL(k_out,    dim3(16384),dim3(256), 0, stream,
                       attn_ws, lse_ws, rwmax, rwsum, out);
}

// Round 6
// 223.439 us; speedup vs baseline: 3.2252x; 1.0219x over previous
//
#include <hip/hip_runtime.h>
#include <math.h>

#define B_  16
#define L_  4096
#define D_  64
#define R_  4
#define NB_ 64
#define BL_ 64

typedef _Float16 f16x8 __attribute__((ext_vector_type(8)));
typedef float    f32x4 __attribute__((ext_vector_type(4)));

// ---------------- ws layout ----------------
// [0MB,1MB)   rmn    double   [B][R][32][64]
// [1MB,2MB)   h      int      [B][R][L]
// [2MB,3MB)   hi     int      [B][R][L]
// [3MB,4MB)   oi     int      [B][R][L]
// [4MB,5MB)   lse    float    [B][R][L]   (original index)
// [5MB,+256)  rwmax  float    [64]
// [5MB+256,)  rwsum  float    [64]
// [6MB,40MB)  attn   _Float16 [B][R][L][64]  (original index)
// [40MB,41MB) rhi    _Float16 [B][128][64]
// [41MB,42MB) rlo    _Float16 [B][128][64]
// [44MB,48MB) meta   int4     [B*R][L]  (hash, pos, pack, packm1) per sorted pos

// K0: normalize rand_matrix along d, store fp64 + split-f16 (hi/lo) copies.
__global__ __launch_bounds__(64) void k_rmnorm(const float* __restrict__ rm,
                                               double* __restrict__ rmn,
                                               _Float16* __restrict__ rhi_g,
                                               _Float16* __restrict__ rlo_g) {
    int blk = blockIdx.x;                 // b*128 + r*32 + n
    int b = blk >> 7, r = (blk >> 5) & 3, n = blk & 31;
    int d = threadIdx.x;
    double v = (double)rm[(((size_t)b * 64 + d) * 4 + r) * 32 + n];
    double sq = v * v;
    #pragma unroll
    for (int off = 32; off > 0; off >>= 1) sq += __shfl_down(sq, off);
    double tot = __shfl(sq, 0);
    double nv = v / sqrt(tot);
    rmn[(((size_t)b * 4 + r) * 32 + n) * 64 + d] = nv;
    float f = (float)nv;
    _Float16 hi = (_Float16)f;
    size_t gi = ((size_t)b * 128 + r * 32 + n) * 64 + d;
    rhi_g[gi] = hi;
    rlo_g[gi] = (_Float16)(f - (float)hi);
}

// K1: split-f16 MFMA hash; S transposed through LDS; per-thread serial argmax
// with exact reference tie semantics; rare per-thread fp64 rescan.
__global__ __launch_bounds__(256, 4) void k_hash(const float* __restrict__ q,
                                                 const double* __restrict__ rmn,
                                                 const _Float16* __restrict__ rhi_g,
                                                 const _Float16* __restrict__ rlo_g,
                                                 int* __restrict__ h_ws) {
    __shared__ __align__(16) char smem[36864];
    _Float16* Rhi = (_Float16*)smem;            // [128][72]
    _Float16* Rlo = (_Float16*)(smem + 18432);  // [128][72]
    float*    Sc  = (float*)smem;               // overlay [64][133] = 34048 B

    int blk = blockIdx.x;                 // b*64 + chunk
    int b = blk >> 6, chunk = blk & 63;
    int tid = threadIdx.x;
    int w = tid >> 6, lane = tid & 63, quad = lane >> 4, l15 = lane & 15;

    {   // stage R split halves
        int row = tid >> 1, dh = (tid & 1) * 32;
        const _Float16* sh = rhi_g + ((size_t)b * 128 + row) * 64 + dh;
        const _Float16* sl = rlo_g + ((size_t)b * 128 + row) * 64 + dh;
        #pragma unroll
        for (int g = 0; g < 4; g++) {
            *(f16x8*)&Rhi[row * 72 + dh + g * 8] = *(const f16x8*)(sh + g * 8);
            *(f16x8*)&Rlo[row * 72 + dh + g * 8] = *(const f16x8*)(sl + g * 8);
        }
    }

    int qrow = chunk * 64 + w * 16 + l15;
    const float* qp = q + ((size_t)(b * L_ + qrow)) * 64;
    f16x8 Ahi[2], Alo[2];
    #pragma unroll
    for (int kt = 0; kt < 2; kt++) {
        float4 t0 = *(const float4*)(qp + kt * 32 + quad * 8);
        float4 t1 = *(const float4*)(qp + kt * 32 + quad * 8 + 4);
        float fv[8] = {t0.x, t0.y, t0.z, t0.w, t1.x, t1.y, t1.z, t1.w};
        #pragma unroll
        for (int j = 0; j < 8; j++) {
            _Float16 hi = (_Float16)fv[j];
            Ahi[kt][j] = hi;
            Alo[kt][j] = (_Float16)(fv[j] - (float)hi);
        }
    }
    __syncthreads();

    f32x4 acc[8];
    #pragma unroll
    for (int jt = 0; jt < 8; jt++) acc[jt] = (f32x4){0.f, 0.f, 0.f, 0.f};
    #pragma unroll
    for (int jt = 0; jt < 8; jt++) {
        #pragma unroll
        for (int kt = 0; kt < 2; kt++) {
            f16x8 bh = *(const f16x8*)&Rhi[(jt * 16 + l15) * 72 + kt * 32 + quad * 8];
            f16x8 bl = *(const f16x8*)&Rlo[(jt * 16 + l15) * 72 + kt * 32 + quad * 8];
            acc[jt] = __builtin_amdgcn_mfma_f32_16x16x32_f16(Ahi[kt], bh, acc[jt], 0, 0, 0);
            acc[jt] = __builtin_amdgcn_mfma_f32_16x16x32_f16(Ahi[kt], bl, acc[jt], 0, 0, 0);
            acc[jt] = __builtin_amdgcn_mfma_f32_16x16x32_f16(Alo[kt], bh, acc[jt], 0, 0, 0);
        }
    }
    __syncthreads();

    #pragma unroll
    for (int jt = 0; jt < 8; jt++) {
        #pragma unroll
        for (int reg = 0; reg < 4; reg++)
            Sc[(w * 16 + quad * 4 + reg) * 133 + jt * 16 + l15] = acc[jt][reg];
    }
    __syncthreads();

    {
        int row = tid & 63, r = tid >> 6;
        const float* sp = &Sc[row * 133 + r * 32];
        float bp = -1e30f, bn = -1e30f; int ip = 0, in2 = 0;
        float v1 = -1e30f, v2 = -1e30f;
        #pragma unroll
        for (int n = 0; n < 32; n++) {
            float v = sp[n], nv = -v;
            if (v > bp)  { bp = v;  ip = n; }
            if (nv > bn) { bn = nv; in2 = n; }
            if (v > v1)       { v2 = v1; v1 = v; }
            else if (v > v2)  { v2 = v; }
            if (nv > v1)      { v2 = v1; v1 = nv; }
            else if (nv > v2) { v2 = nv; }
        }
        int i1 = (bp >= bn) ? ip : (32 + in2);
        int l = chunk * 64 + row;
        if (v1 - v2 < 4e-5f) {
            const float* qr = q + ((size_t)(b * L_ + l)) * 64;
            const double* src = rmn + ((size_t)(b * 4 + r)) * 2048;
            double bpd = -1e300, bnd = -1e300; int ipd = 0, ind = 0;
            for (int n = 0; n < 32; n++) {
                const double* rp = &src[n * 64];
                double a2 = 0.0;
                for (int d = 0; d < 64; d++) a2 += (double)qr[d] * rp[d];
                if (a2 > bpd)  { bpd = a2;  ipd = n; }
                if (-a2 > bnd) { bnd = -a2; ind = n; }
            }
            i1 = (bpd >= bnd) ? ipd : (32 + ind);
        }
        h_ws[((size_t)(b * 4 + r)) * L_ + l] = i1;
    }
}

// K2: stable counting sort per (b,r)
__global__ __launch_bounds__(64) void k_sort(const int* __restrict__ h_ws,
                                             int* __restrict__ hi_ws,
                                             int* __restrict__ oi_ws) {
    __shared__ int hs[64 * 65];
    __shared__ int cnt[64 * 65];
    int br = blockIdx.x;
    const int* hp = h_ws + (size_t)br * L_;
    int t = threadIdx.x;
    for (int w = 0; w < 64; w++) hs[w * 65 + t] = hp[w * 64 + t];
    for (int u = 0; u < 64; u++) cnt[t * 65 + u] = 0;
    __syncthreads();
    for (int k = 0; k < 64; k++) cnt[t * 65 + hs[t * 65 + k]]++;
    __syncthreads();
    int cs = 0;
    for (int c = 0; c < 64; c++) cs += cnt[c * 65 + t];
    int v = cs;
    #pragma unroll
    for (int off = 1; off < 64; off <<= 1) {
        int u = __shfl_up(v, off);
        if (t >= off) v += u;
    }
    int running = v - cs;
    for (int c = 0; c < 64; c++) {
        int tmp = cnt[c * 65 + t];
        cnt[c * 65 + t] = running;
        running += tmp;
    }
    __syncthreads();
    int* hi = hi_ws + (size_t)br * L_;
    int* oi = oi_ws + (size_t)br * L_;
    for (int k = 0; k < 64; k++) {
        int idx = t * 64 + k;
        int b2 = hs[t * 65 + k];
        int pos = cnt[t * 65 + b2]++;
        hi[pos] = idx;
        oi[idx] = pos;
    }
}

// K2b: per sorted position, gather (hash, orig pos, packed buckets, packed-1).
__global__ __launch_bounds__(256) void k_meta(const int* __restrict__ h_ws,
                                              const int* __restrict__ hi_ws,
                                              const int* __restrict__ oi_ws,
                                              int4* __restrict__ meta_ws) {
    int gid = blockIdx.x * 256 + threadIdx.x;   // [0, 64*4096)
    int br = gid >> 12, spos = gid & 4095;
    int b = br >> 2;
    int p = hi_ws[(size_t)br * L_ + spos];
    int hh = h_ws[(size_t)br * L_ + p];
    int pack = 0, packm1 = 0;
    #pragma unroll
    for (int r2 = 0; r2 < 4; r2++) {
        int bk = oi_ws[((size_t)(b * 4 + r2)) * L_ + p] >> 6;
        pack   |= bk << (8 * r2);
        packm1 |= ((bk + 63) & 63) << (8 * r2);
    }
    meta_ws[(size_t)br * L_ + spos] = make_int4(hh, p, pack, packm1);
}

// K3: MFMA fused attention per (b, chunk, round). XCD-swizzled blocks; Q A-frags
// direct from global; K (LDS, overlaid by P) + V^T (LDS); f16 attn output.
__global__ __launch_bounds__(256, 4) void k_attn(const float* __restrict__ query,
                                                 const float* __restrict__ value,
                                                 const int4* __restrict__ meta_ws,
                                                 float* __restrict__ lse_ws,
                                                 _Float16* __restrict__ attn_ws) {
    __shared__ _Float16 Ksh[128 * 72];    // 18432 B; overlaid by Ph[64][136] (17408 B)
    __shared__ _Float16 Vt[64 * 136];     // 17408 B
    __shared__ int4 kmeta[128];           // 2048 B

    // XCD swizzle: xcd = blockIdx&7 serves b = xcd*2 + (slot>>8) only
    int xcd = blockIdx.x & 7, slot = blockIdx.x >> 3;
    int b = xcd * 2 + (slot >> 8);
    int rem = slot & 255, n = rem >> 2, r = rem & 3;
    int tid = threadIdx.x;
    int w = tid >> 6, lane = tid & 63, quad = lane >> 4, l15 = lane & 15;
    int hibase = (b * 4 + r) * L_;

    if (tid < 128) {
        int j = tid;
        int nprev = (n + 63) & 63;
        int spos = (j < 64) ? (nprev * 64 + j) : (n * 64 + (j - 64));
        kmeta[j] = meta_ws[hibase + spos];
    }
    __syncthreads();

    {   // stage K (scaled f16) + V^T: 2 threads per row
        int j = tid >> 1, dh = (tid & 1) * 32;
        int p = kmeta[j].y;
        const float4* qrow = (const float4*)(query + ((size_t)(b * L_ + p)) * 64 + dh);
        const float4* vrow = (const float4*)(value + ((size_t)(b * L_ + p)) * 64 + dh);
        float qv[32];
        float ss = 0.f;
        #pragma unroll
        for (int c = 0; c < 8; c++) {
            float4 t = qrow[c];
            qv[4*c+0] = t.x; qv[4*c+1] = t.y; qv[4*c+2] = t.z; qv[4*c+3] = t.w;
            ss += t.x*t.x + t.y*t.y + t.z*t.z + t.w*t.w;
        }
        ss += __shfl_xor(ss, 1);
        float nr = sqrtf(ss); if (nr < 1e-12f) nr = 1e-12f;
        float kscale = 0.125f / nr;
        #pragma unroll
        for (int g = 0; g < 4; g++) {
            f16x8 hv;
            #pragma unroll
            for (int t2 = 0; t2 < 8; t2++) hv[t2] = (_Float16)(qv[g*8+t2] * kscale);
            *(f16x8*)&Ksh[j * 72 + dh + g * 8] = hv;
        }
        float vv[32];
        #pragma unroll
        for (int c = 0; c < 8; c++) {
            float4 t = vrow[c];
            vv[4*c+0] = t.x; vv[4*c+1] = t.y; vv[4*c+2] = t.z; vv[4*c+3] = t.w;
        }
        #pragma unroll
        for (int t2 = 0; t2 < 32; t2++) Vt[(dh + t2) * 136 + j] = (_Float16)vv[t2];
    }

    // Q A-frags direct from global (row = gathered pos of q-row w*16+l15)
    int4 qmw = kmeta[64 + w * 16 + l15];
    const float* qp = query + ((size_t)(b * L_ + qmw.y)) * 64;
    f16x8 afr[2];
    #pragma unroll
    for (int kt = 0; kt < 2; kt++) {
        float4 t0 = *(const float4*)(qp + kt * 32 + quad * 8);
        float4 t1 = *(const float4*)(qp + kt * 32 + quad * 8 + 4);
        float fv[8] = {t0.x, t0.y, t0.z, t0.w, t1.x, t1.y, t1.z, t1.w};
        #pragma unroll
        for (int j = 0; j < 8; j++) afr[kt][j] = (_Float16)fv[j];
    }
    __syncthreads();

    f32x4 acc[8];
    #pragma unroll
    for (int jt = 0; jt < 8; jt++) acc[jt] = (f32x4){0.f, 0.f, 0.f, 0.f};
    #pragma unroll
    for (int jt = 0; jt < 8; jt++) {
        #pragma unroll
        for (int kt = 0; kt < 2; kt++) {
            f16x8 bfr = *(const f16x8*)&Ksh[(jt * 16 + l15) * 72 + kt * 32 + quad * 8];
            acc[jt] = __builtin_amdgcn_mfma_f32_16x16x32_f16(afr[kt], bfr, acc[jt], 0, 0, 0);
        }
    }

    int4 qm4[4], km4[8];
    #pragma unroll
    for (int reg = 0; reg < 4; reg++) qm4[reg] = kmeta[64 + w * 16 + quad * 4 + reg];
    #pragma unroll
    for (int jt = 0; jt < 8; jt++) km4[jt] = kmeta[jt * 16 + l15];
    __syncthreads();                      // QK reads of Ksh done -> overlay

    _Float16* Ph = Ksh;                   // [64][136]
    float lse_r[4];
    #pragma unroll
    for (int reg = 0; reg < 4; reg++) {
        float s[8];
        #pragma unroll
        for (int jt = 0; jt < 8; jt++) {
            float v = acc[jt][reg];
            if (km4[jt].x != qm4[reg].x) v = -1e9f;
            if (qm4[reg].y < km4[jt].y)  v = -1e9f;
            if (qm4[reg].y == km4[jt].y) v = -1e5f;
            s[jt] = v;
        }
        float m = s[0];
        #pragma unroll
        for (int jt = 1; jt < 8; jt++) m = fmaxf(m, s[jt]);
        #pragma unroll
        for (int off = 1; off < 16; off <<= 1) m = fmaxf(m, __shfl_xor(m, off));
        float te[8], sum = 0.f;
        #pragma unroll
        for (int jt = 0; jt < 8; jt++) { te[jt] = __expf(s[jt] - m); sum += te[jt]; }
        #pragma unroll
        for (int off = 1; off < 16; off <<= 1) sum += __shfl_xor(sum, off);
        float inv = 1.f / sum;
        lse_r[reg] = m + __logf(sum);
        int i = w * 16 + quad * 4 + reg;
        #pragma unroll
        for (int jt = 0; jt < 8; jt++) {
            int z1 = km4[jt].z ^ qm4[reg].z;
            int z2 = km4[jt].z ^ qm4[reg].w;
            int nz = __popc((z1 + 0x7f7f7f7f) & 0x80808080)
                   + __popc((z2 + 0x7f7f7f7f) & 0x80808080);
            float p = te[jt] * inv / (float)(8 - nz);
            Ph[i * 136 + jt * 16 + l15] = (_Float16)p;
        }
    }
    if (l15 == 0) {
        #pragma unroll
        for (int reg = 0; reg < 4; reg++)
            lse_ws[hibase + qm4[reg].y] = lse_r[reg];
    }
    __syncthreads();

    f32x4 oacc[4];
    #pragma unroll
    for (int nt = 0; nt < 4; nt++) oacc[nt] = (f32x4){0.f, 0.f, 0.f, 0.f};
    #pragma unroll
    for (int kt = 0; kt < 4; kt++) {
        f16x8 pa = *(const f16x8*)&Ph[(w * 16 + l15) * 136 + kt * 32 + quad * 8];
        #pragma unroll
        for (int nt = 0; nt < 4; nt++) {
            f16x8 vb = *(const f16x8*)&Vt[(nt * 16 + l15) * 136 + kt * 32 + quad * 8];
            oacc[nt] = __builtin_amdgcn_mfma_f32_16x16x32_f16(pa, vb, oacc[nt], 0, 0, 0);
        }
    }
    #pragma unroll
    for (int reg = 0; reg < 4; reg++) {
        size_t base = (((size_t)(b * 4 + r)) * L_ + qm4[reg].y) * 64;
        #pragma unroll
        for (int nt = 0; nt < 4; nt++)
            attn_ws[base + nt * 16 + l15] = (_Float16)oacc[nt][reg];
    }
}

// K4a: per (b,r) softmax-over-L stats of lse
__global__ __launch_bounds__(256) void k_rw(const float* __restrict__ lse_ws,
                                            float* __restrict__ rwmax,
                                            float* __restrict__ rwsum) {
    __shared__ float  red[256];
    __shared__ double redd[256];
    int br = blockIdx.x;
    const float* lp = lse_ws + (size_t)br * L_;
    int t = threadIdx.x;
    float m = -1e30f;
    for (int k = t; k < L_; k += 256) m = fmaxf(m, lp[k]);
    red[t] = m; __syncthreads();
    for (int s2 = 128; s2 > 0; s2 >>= 1) {
        if (t < s2) red[t] = fmaxf(red[t], red[t + s2]);
        __syncthreads();
    }
    float mm = red[0];
    double s = 0.0;
    for (int k = t; k < L_; k += 256) s += (double)expf(lp[k] - mm);
    redd[t] = s; __syncthreads();
    for (int s2 = 128; s2 > 0; s2 >>= 1) {
        if (t < s2) redd[t] += redd[t + s2];
        __syncthreads();
    }
    if (t == 0) { rwmax[br] = mm; rwsum[br] = (float)redd[0]; }
}

// K4b: out[b,l,d] = sum_r attn[b,r,l,d] * softmax_L(lse)[b,r,l]
__global__ __launch_bounds__(256) void k_out(const _Float16* __restrict__ attn_ws,
                                             const float* __restrict__ lse_ws,
                                             const float* __restrict__ rwmax,
                                             const float* __restrict__ rwsum,
                                             float* __restrict__ out) {
    size_t gid = (size_t)blockIdx.x * 256 + threadIdx.x;
    int d = (int)(gid & 63);
    size_t row = gid >> 6;
    int b = (int)(row >> 12), l = (int)(row & 4095);
    float o = 0.f;
    #pragma unroll
    for (int r = 0; r < 4; r++) {
        int br = b * 4 + r;
        float w = expf(lse_ws[(size_t)br * L_ + l] - rwmax[br]) / rwsum[br];
        o += (float)attn_ws[(((size_t)br * L_ + l) << 6) + d] * w;
    }
    out[gid] = o;
}

extern "C" void kernel_launch(void* const* d_in, const int* in_sizes, int n_in,
                              void* d_out, int out_size, void* d_ws, size_t ws_size,
                              hipStream_t stream) {
    const float* query = (const float*)d_in[0];
    const float* value = (const float*)d_in[1];
    const float* rm    = (const float*)d_in[2];
    char* ws = (char*)d_ws;
    double*    rmn    = (double*)ws;
    int*       h_ws   = (int*)(ws + ((size_t)1 << 20));
    int*       hi_ws  = (int*)(ws + ((size_t)2 << 20));
    int*       oi_ws  = (int*)(ws + ((size_t)3 << 20));
    float*     lse_ws = (float*)(ws + ((size_t)4 << 20));
    float*     rwmax  = (float*)(ws + ((size_t)5 << 20));
    float*     rwsum  = (float*)(ws + ((size_t)5 << 20) + 256);
    _Float16*  attn_ws= (_Float16*)(ws + ((size_t)6 << 20));
    _Float16*  rhi_g  = (_Float16*)(ws + ((size_t)40 << 20));
    _Float16*  rlo_g  = (_Float16*)(ws + ((size_t)41 << 20));
    int4*      meta_ws= (int4*)(ws + ((size_t)44 << 20));
    float*     out    = (float*)d_out;

    hipLaunchKernelGGL(k_rmnorm, dim3(2048), dim3(64),  0, stream, rm, rmn, rhi_g, rlo_g);
    hipLaunchKernelGGL(k_hash,   dim3(1024), dim3(256), 0, stream, query, rmn, rhi_g, rlo_g, h_ws);
    hipLaunchKernelGGL(k_sort,   dim3(64),   dim3(64),  0, stream, h_ws, hi_ws, oi_ws);
    hipLaunchKernelGGL(k_meta,   dim3(1024), dim3(256), 0, stream, h_ws, hi_ws, oi_ws, meta_ws);
    hipLaunchKernelGGL(k_attn,   dim3(4096), dim3(256), 0, stream,
                       query, value, meta_ws, lse_ws, attn_ws);
    hipLaunchKernelGGL(k_rw,     dim3(64),   dim3(256), 0, stream, lse_ws, rwmax, rwsum);
    hipLaunchKernelGGL(k_out,    dim3(16384),dim3(256), 0, stream,
                       attn_ws, lse_ws, rwmax, rwsum, out);
}

// Round 7
// 175.919 us; speedup vs baseline: 4.0964x; 1.2701x over previous
//
#include <hip/hip_runtime.h>
#include <math.h>

#define B_  16
#define L_  4096
#define D_  64
#define R_  4
#define NB_ 64
#define BL_ 64
#define FIXCAP 8192

typedef _Float16 f16x8 __attribute__((ext_vector_type(8)));
typedef _Float16 f16x2 __attribute__((ext_vector_type(2)));
typedef float    f32x4 __attribute__((ext_vector_type(4)));

// ---------------- ws layout ----------------
// [0MB,1MB)   rmn    double   [B][R][32][64]
// [1MB,2MB)   h      int      [B][R][L]
// [2MB,3MB)   hi     int      [B][R][L]
// [3MB,4MB)   oi     int      [B][R][L]
// [4MB,5MB)   lse    float    [B][R][L]   (original index)
// [5MB,+256)  rwmax  float[64];  [+256,+512) rwsum float[64];  [+512] fix_cnt
// [5MB+1024,) fix_list int[FIXCAP]
// [6MB,40MB)  attn   _Float16 [B][R][L][64]  (original index)
// [40MB,41MB) rhi    _Float16 [B][128][64]
// [41MB,42MB) rlo    _Float16 [B][128][64]
// [44MB,48MB) meta   int4     [B*R][L]

// K0: normalize rand_matrix along d, store fp64 + split-f16 copies; zero fix_cnt.
__global__ __launch_bounds__(64) void k_rmnorm(const float* __restrict__ rm,
                                               double* __restrict__ rmn,
                                               _Float16* __restrict__ rhi_g,
                                               _Float16* __restrict__ rlo_g,
                                               int* __restrict__ fix_cnt) {
    if (blockIdx.x == 0 && threadIdx.x == 0) *fix_cnt = 0;
    int blk = blockIdx.x;                 // b*128 + r*32 + n
    int b = blk >> 7, r = (blk >> 5) & 3, n = blk & 31;
    int d = threadIdx.x;
    double v = (double)rm[(((size_t)b * 64 + d) * 4 + r) * 32 + n];
    double sq = v * v;
    #pragma unroll
    for (int off = 32; off > 0; off >>= 1) sq += __shfl_down(sq, off);
    double tot = __shfl(sq, 0);
    double nv = v / sqrt(tot);
    rmn[(((size_t)b * 4 + r) * 32 + n) * 64 + d] = nv;
    float f = (float)nv;
    _Float16 hi = (_Float16)f;
    size_t gi = ((size_t)b * 128 + r * 32 + n) * 64 + d;
    rhi_g[gi] = hi;
    rlo_g[gi] = (_Float16)(f - (float)hi);
}

// K1: split-f16 MFMA hash; small-margin rows appended to fix list (no fp64 here).
__global__ __launch_bounds__(256, 4) void k_hash(const float* __restrict__ q,
                                                 const _Float16* __restrict__ rhi_g,
                                                 const _Float16* __restrict__ rlo_g,
                                                 int* __restrict__ h_ws,
                                                 int* __restrict__ fix_cnt,
                                                 int* __restrict__ fix_list) {
    __shared__ __align__(16) char smem[36864];
    _Float16* Rhi = (_Float16*)smem;            // [128][72]
    _Float16* Rlo = (_Float16*)(smem + 18432);  // [128][72]
    float*    Sc  = (float*)smem;               // overlay [64][133]

    int blk = blockIdx.x;                 // b*64 + chunk
    int b = blk >> 6, chunk = blk & 63;
    int tid = threadIdx.x;
    int w = tid >> 6, lane = tid & 63, quad = lane >> 4, l15 = lane & 15;

    {   // stage R split halves
        int row = tid >> 1, dh = (tid & 1) * 32;
        const _Float16* sh = rhi_g + ((size_t)b * 128 + row) * 64 + dh;
        const _Float16* sl = rlo_g + ((size_t)b * 128 + row) * 64 + dh;
        #pragma unroll
        for (int g = 0; g < 4; g++) {
            *(f16x8*)&Rhi[row * 72 + dh + g * 8] = *(const f16x8*)(sh + g * 8);
            *(f16x8*)&Rlo[row * 72 + dh + g * 8] = *(const f16x8*)(sl + g * 8);
        }
    }

    int qrow = chunk * 64 + w * 16 + l15;
    const float* qp = q + ((size_t)(b * L_ + qrow)) * 64;
    f16x8 Ahi[2], Alo[2];
    #pragma unroll
    for (int kt = 0; kt < 2; kt++) {
        float4 t0 = *(const float4*)(qp + kt * 32 + quad * 8);
        float4 t1 = *(const float4*)(qp + kt * 32 + quad * 8 + 4);
        float fv[8] = {t0.x, t0.y, t0.z, t0.w, t1.x, t1.y, t1.z, t1.w};
        #pragma unroll
        for (int j = 0; j < 8; j++) {
            _Float16 hi = (_Float16)fv[j];
            Ahi[kt][j] = hi;
            Alo[kt][j] = (_Float16)(fv[j] - (float)hi);
        }
    }
    __syncthreads();

    f32x4 acc[8];
    #pragma unroll
    for (int jt = 0; jt < 8; jt++) acc[jt] = (f32x4){0.f, 0.f, 0.f, 0.f};
    #pragma unroll
    for (int jt = 0; jt < 8; jt++) {
        #pragma unroll
        for (int kt = 0; kt < 2; kt++) {
            f16x8 bh = *(const f16x8*)&Rhi[(jt * 16 + l15) * 72 + kt * 32 + quad * 8];
            f16x8 bl = *(const f16x8*)&Rlo[(jt * 16 + l15) * 72 + kt * 32 + quad * 8];
            acc[jt] = __builtin_amdgcn_mfma_f32_16x16x32_f16(Ahi[kt], bh, acc[jt], 0, 0, 0);
            acc[jt] = __builtin_amdgcn_mfma_f32_16x16x32_f16(Ahi[kt], bl, acc[jt], 0, 0, 0);
            acc[jt] = __builtin_amdgcn_mfma_f32_16x16x32_f16(Alo[kt], bh, acc[jt], 0, 0, 0);
        }
    }
    __syncthreads();

    #pragma unroll
    for (int jt = 0; jt < 8; jt++) {
        #pragma unroll
        for (int reg = 0; reg < 4; reg++)
            Sc[(w * 16 + quad * 4 + reg) * 133 + jt * 16 + l15] = acc[jt][reg];
    }
    __syncthreads();

    {
        int row = tid & 63, r = tid >> 6;
        const float* sp = &Sc[row * 133 + r * 32];
        float bp = -1e30f, bn = -1e30f; int ip = 0, in2 = 0;
        float v1 = -1e30f, v2 = -1e30f;
        #pragma unroll
        for (int n = 0; n < 32; n++) {
            float v = sp[n], nv = -v;
            if (v > bp)  { bp = v;  ip = n; }
            if (nv > bn) { bn = nv; in2 = n; }
            if (v > v1)       { v2 = v1; v1 = v; }
            else if (v > v2)  { v2 = v; }
            if (nv > v1)      { v2 = v1; v1 = nv; }
            else if (nv > v2) { v2 = nv; }
        }
        int i1 = (bp >= bn) ? ip : (32 + in2);
        int l = chunk * 64 + row;
        h_ws[((size_t)(b * 4 + r)) * L_ + l] = i1;
        if (v1 - v2 < 4e-5f) {            // defer exact resolve to k_fix
            int slot = atomicAdd(fix_cnt, 1);
            if (slot < FIXCAP) fix_list[slot] = (b << 14) | (r << 12) | l;
        }
    }
}

// K1b: exact fp64 resolve, one wave per flagged row. lane = concat candidate.
__global__ __launch_bounds__(64) void k_fix(const float* __restrict__ q,
                                            const double* __restrict__ rmn,
                                            const int* __restrict__ fix_cnt,
                                            const int* __restrict__ fix_list,
                                            int* __restrict__ h_ws) {
    int cnt = *fix_cnt; if (cnt > FIXCAP) cnt = FIXCAP;
    int lane = threadIdx.x;
    for (int i = blockIdx.x; i < cnt; i += gridDim.x) {
        int e = fix_list[i];
        int b = e >> 14, r = (e >> 12) & 3, l = e & 4095;
        int n = lane & 31;
        const double* rp = rmn + ((size_t)(b * 4 + r)) * 2048 + n * 64;
        const float* qr = q + ((size_t)(b * L_ + l)) * 64;
        double a0 = 0.0, a1 = 0.0, a2 = 0.0, a3 = 0.0;
        #pragma unroll
        for (int d = 0; d < 64; d += 4) {
            a0 += (double)qr[d]   * rp[d];
            a1 += (double)qr[d+1] * rp[d+1];
            a2 += (double)qr[d+2] * rp[d+2];
            a3 += (double)qr[d+3] * rp[d+3];
        }
        double acc = ((a0 + a1) + (a2 + a3));
        // match reference sum order: plain sequential fp64 is within 1e-16 of any
        // order; gap==0 across distinct candidates is measure-zero.
        double v = (lane < 32) ? acc : -acc;
        int idx = lane;                   // concat index
        #pragma unroll
        for (int off = 1; off < 64; off <<= 1) {
            double ov = __shfl_xor(v, off);
            int   oidx = __shfl_xor(idx, off);
            if (ov > v || (ov == v && oidx < idx)) { v = ov; idx = oidx; }
        }
        if (lane == 0) h_ws[((size_t)(b * 4 + r)) * L_ + l] = idx;
    }
}

// K2: stable counting sort per (b,r)
__global__ __launch_bounds__(64) void k_sort(const int* __restrict__ h_ws,
                                             int* __restrict__ hi_ws,
                                             int* __restrict__ oi_ws) {
    __shared__ int hs[64 * 65];
    __shared__ int cnt[64 * 65];
    int br = blockIdx.x;
    const int* hp = h_ws + (size_t)br * L_;
    int t = threadIdx.x;
    for (int w = 0; w < 64; w++) hs[w * 65 + t] = hp[w * 64 + t];
    for (int u = 0; u < 64; u++) cnt[t * 65 + u] = 0;
    __syncthreads();
    for (int k = 0; k < 64; k++) cnt[t * 65 + hs[t * 65 + k]]++;
    __syncthreads();
    int cs = 0;
    for (int c = 0; c < 64; c++) cs += cnt[c * 65 + t];
    int v = cs;
    #pragma unroll
    for (int off = 1; off < 64; off <<= 1) {
        int u = __shfl_up(v, off);
        if (t >= off) v += u;
    }
    int running = v - cs;
    for (int c = 0; c < 64; c++) {
        int tmp = cnt[c * 65 + t];
        cnt[c * 65 + t] = running;
        running += tmp;
    }
    __syncthreads();
    int* hi = hi_ws + (size_t)br * L_;
    int* oi = oi_ws + (size_t)br * L_;
    for (int k = 0; k < 64; k++) {
        int idx = t * 64 + k;
        int b2 = hs[t * 65 + k];
        int pos = cnt[t * 65 + b2]++;
        hi[pos] = idx;
        oi[idx] = pos;
    }
}

// K2b: per sorted position meta record
__global__ __launch_bounds__(256) void k_meta(const int* __restrict__ h_ws,
                                              const int* __restrict__ hi_ws,
                                              const int* __restrict__ oi_ws,
                                              int4* __restrict__ meta_ws) {
    int gid = blockIdx.x * 256 + threadIdx.x;
    int br = gid >> 12, spos = gid & 4095;
    int b = br >> 2;
    int p = hi_ws[(size_t)br * L_ + spos];
    int hh = h_ws[(size_t)br * L_ + p];
    int pack = 0, packm1 = 0;
    #pragma unroll
    for (int r2 = 0; r2 < 4; r2++) {
        int bk = oi_ws[((size_t)(b * 4 + r2)) * L_ + p] >> 6;
        pack   |= bk << (8 * r2);
        packm1 |= ((bk + 63) & 63) << (8 * r2);
    }
    meta_ws[(size_t)br * L_ + spos] = make_int4(hh, p, pack, packm1);
}

// K3: MFMA fused attention, XCD-swizzled; V staged via row-pair ushort2 writes.
__global__ __launch_bounds__(256, 4) void k_attn(const float* __restrict__ query,
                                                 const float* __restrict__ value,
                                                 const int4* __restrict__ meta_ws,
                                                 float* __restrict__ lse_ws,
                                                 _Float16* __restrict__ attn_ws) {
    __shared__ _Float16 Ksh[128 * 72];    // 18432 B; overlaid by Ph[64][136]
    __shared__ _Float16 Vt[64 * 136];     // 17408 B
    __shared__ int4 kmeta[128];

    int xcd = blockIdx.x & 7, slot = blockIdx.x >> 3;
    int b = xcd * 2 + (slot >> 8);
    int rem = slot & 255, n = rem >> 2, r = rem & 3;
    int tid = threadIdx.x;
    int w = tid >> 6, lane = tid & 63, quad = lane >> 4, l15 = lane & 15;
    int hibase = (b * 4 + r) * L_;

    if (tid < 128) {
        int j = tid;
        int nprev = (n + 63) & 63;
        int spos = (j < 64) ? (nprev * 64 + j) : (n * 64 + (j - 64));
        kmeta[j] = meta_ws[hibase + spos];
    }
    __syncthreads();

    {   // stage K (scaled f16): 2 threads per row
        int j = tid >> 1, dh = (tid & 1) * 32;
        int p = kmeta[j].y;
        const float4* qrow = (const float4*)(query + ((size_t)(b * L_ + p)) * 64 + dh);
        float qv[32];
        float ss = 0.f;
        #pragma unroll
        for (int c = 0; c < 8; c++) {
            float4 t = qrow[c];
            qv[4*c+0] = t.x; qv[4*c+1] = t.y; qv[4*c+2] = t.z; qv[4*c+3] = t.w;
            ss += t.x*t.x + t.y*t.y + t.z*t.z + t.w*t.w;
        }
        ss += __shfl_xor(ss, 1);
        float nr = sqrtf(ss); if (nr < 1e-12f) nr = 1e-12f;
        float kscale = 0.125f / nr;
        #pragma unroll
        for (int g = 0; g < 4; g++) {
            f16x8 hv;
            #pragma unroll
            for (int t2 = 0; t2 < 8; t2++) hv[t2] = (_Float16)(qv[g*8+t2] * kscale);
            *(f16x8*)&Ksh[j * 72 + dh + g * 8] = hv;
        }
    }
    {   // stage V^T: thread = (row-pair m, d-quarter sub); 16 ushort2 writes
        int m = tid >> 2, sub = tid & 3;
        int p0 = kmeta[2 * m].y, p1 = kmeta[2 * m + 1].y;
        const float4* v0p = (const float4*)(value + ((size_t)(b * L_ + p0)) * 64 + sub * 16);
        const float4* v1p = (const float4*)(value + ((size_t)(b * L_ + p1)) * 64 + sub * 16);
        float a0[16], a1[16];
        #pragma unroll
        for (int c = 0; c < 4; c++) {
            float4 t0 = v0p[c], t1 = v1p[c];
            a0[4*c+0]=t0.x; a0[4*c+1]=t0.y; a0[4*c+2]=t0.z; a0[4*c+3]=t0.w;
            a1[4*c+0]=t1.x; a1[4*c+1]=t1.y; a1[4*c+2]=t1.z; a1[4*c+3]=t1.w;
        }
        #pragma unroll
        for (int d = 0; d < 16; d++) {
            f16x2 hv = { (_Float16)a0[d], (_Float16)a1[d] };
            *(f16x2*)&Vt[(sub * 16 + d) * 136 + 2 * m] = hv;
        }
    }

    // Q A-frags direct from global
    int4 qmw = kmeta[64 + w * 16 + l15];
    const float* qp = query + ((size_t)(b * L_ + qmw.y)) * 64;
    f16x8 afr[2];
    #pragma unroll
    for (int kt = 0; kt < 2; kt++) {
        float4 t0 = *(const float4*)(qp + kt * 32 + quad * 8);
        float4 t1 = *(const float4*)(qp + kt * 32 + quad * 8 + 4);
        float fv[8] = {t0.x, t0.y, t0.z, t0.w, t1.x, t1.y, t1.z, t1.w};
        #pragma unroll
        for (int j = 0; j < 8; j++) afr[kt][j] = (_Float16)fv[j];
    }
    __syncthreads();

    f32x4 acc[8];
    #pragma unroll
    for (int jt = 0; jt < 8; jt++) acc[jt] = (f32x4){0.f, 0.f, 0.f, 0.f};
    #pragma unroll
    for (int jt = 0; jt < 8; jt++) {
        #pragma unroll
        for (int kt = 0; kt < 2; kt++) {
            f16x8 bfr = *(const f16x8*)&Ksh[(jt * 16 + l15) * 72 + kt * 32 + quad * 8];
            acc[jt] = __builtin_amdgcn_mfma_f32_16x16x32_f16(afr[kt], bfr, acc[jt], 0, 0, 0);
        }
    }

    int4 qm4[4], km4[8];
    #pragma unroll
    for (int reg = 0; reg < 4; reg++) qm4[reg] = kmeta[64 + w * 16 + quad * 4 + reg];
    #pragma unroll
    for (int jt = 0; jt < 8; jt++) km4[jt] = kmeta[jt * 16 + l15];
    __syncthreads();                      // QK reads of Ksh done -> overlay

    _Float16* Ph = Ksh;
    float lse_r[4];
    #pragma unroll
    for (int reg = 0; reg < 4; reg++) {
        float s[8];
        #pragma unroll
        for (int jt = 0; jt < 8; jt++) {
            float v = acc[jt][reg];
            if (km4[jt].x != qm4[reg].x) v = -1e9f;
            if (qm4[reg].y < km4[jt].y)  v = -1e9f;
            if (qm4[reg].y == km4[jt].y) v = -1e5f;
            s[jt] = v;
        }
        float m = s[0];
        #pragma unroll
        for (int jt = 1; jt < 8; jt++) m = fmaxf(m, s[jt]);
        #pragma unroll
        for (int off = 1; off < 16; off <<= 1) m = fmaxf(m, __shfl_xor(m, off));
        float te[8], sum = 0.f;
        #pragma unroll
        for (int jt = 0; jt < 8; jt++) { te[jt] = __expf(s[jt] - m); sum += te[jt]; }
        #pragma unroll
        for (int off = 1; off < 16; off <<= 1) sum += __shfl_xor(sum, off);
        float inv = 1.f / sum;
        lse_r[reg] = m + __logf(sum);
        int i = w * 16 + quad * 4 + reg;
        #pragma unroll
        for (int jt = 0; jt < 8; jt++) {
            int z1 = km4[jt].z ^ qm4[reg].z;
            int z2 = km4[jt].z ^ qm4[reg].w;
            int nz = __popc((z1 + 0x7f7f7f7f) & 0x80808080)
                   + __popc((z2 + 0x7f7f7f7f) & 0x80808080);
            float p = te[jt] * inv / (float)(8 - nz);
            Ph[i * 136 + jt * 16 + l15] = (_Float16)p;
        }
    }
    if (l15 == 0) {
        #pragma unroll
        for (int reg = 0; reg < 4; reg++)
            lse_ws[hibase + qm4[reg].y] = lse_r[reg];
    }
    __syncthreads();

    f32x4 oacc[4];
    #pragma unroll
    for (int nt = 0; nt < 4; nt++) oacc[nt] = (f32x4){0.f, 0.f, 0.f, 0.f};
    #pragma unroll
    for (int kt = 0; kt < 4; kt++) {
        f16x8 pa = *(const f16x8*)&Ph[(w * 16 + l15) * 136 + kt * 32 + quad * 8];
        #pragma unroll
        for (int nt = 0; nt < 4; nt++) {
            f16x8 vb = *(const f16x8*)&Vt[(nt * 16 + l15) * 136 + kt * 32 + quad * 8];
            oacc[nt] = __builtin_amdgcn_mfma_f32_16x16x32_f16(pa, vb, oacc[nt], 0, 0, 0);
        }
    }
    #pragma unroll
    for (int reg = 0; reg < 4; reg++) {
        size_t base = (((size_t)(b * 4 + r)) * L_ + qm4[reg].y) * 64;
        #pragma unroll
        for (int nt = 0; nt < 4; nt++)
            attn_ws[base + nt * 16 + l15] = (_Float16)oacc[nt][reg];
    }
}

// K4a: per (b,r) softmax-over-L stats of lse
__global__ __launch_bounds__(256) void k_rw(const float* __restrict__ lse_ws,
                                            float* __restrict__ rwmax,
                                            float* __restrict__ rwsum) {
    __shared__ float  red[256];
    __shared__ double redd[256];
    int br = blockIdx.x;
    const float* lp = lse_ws + (size_t)br * L_;
    int t = threadIdx.x;
    float m = -1e30f;
    for (int k = t; k < L_; k += 256) m = fmaxf(m, lp[k]);
    red[t] = m; __syncthreads();
    for (int s2 = 128; s2 > 0; s2 >>= 1) {
        if (t < s2) red[t] = fmaxf(red[t], red[t + s2]);
        __syncthreads();
    }
    float mm = red[0];
    double s = 0.0;
    for (int k = t; k < L_; k += 256) s += (double)expf(lp[k] - mm);
    redd[t] = s; __syncthreads();
    for (int s2 = 128; s2 > 0; s2 >>= 1) {
        if (t < s2) redd[t] += redd[t + s2];
        __syncthreads();
    }
    if (t == 0) { rwmax[br] = mm; rwsum[br] = (float)redd[0]; }
}

// K4b: vectorized combine — thread = (b,l, d-octet)
__global__ __launch_bounds__(256) void k_out(const _Float16* __restrict__ attn_ws,
                                             const float* __restrict__ lse_ws,
                                             const float* __restrict__ rwmax,
                                             const float* __restrict__ rwsum,
                                             float* __restrict__ out) {
    int gid = blockIdx.x * 256 + threadIdx.x;   // B*L*8
    int g = gid & 7;
    size_t row = (size_t)(gid >> 3);            // b*L + l
    int b = (int)(row >> 12), l = (int)(row & 4095);
    float o[8];
    #pragma unroll
    for (int k = 0; k < 8; k++) o[k] = 0.f;
    #pragma unroll
    for (int r = 0; r < 4; r++) {
        int br = b * 4 + r;
        float wgt = __expf(lse_ws[(size_t)br * L_ + l] - rwmax[br]) / rwsum[br];
        f16x8 av = *(const f16x8*)&attn_ws[(((size_t)br * L_ + l) << 6) + g * 8];
        #pragma unroll
        for (int k = 0; k < 8; k++) o[k] += (float)av[k] * wgt;
    }
    float4* op = (float4*)(out + row * 64 + g * 8);
    op[0] = make_float4(o[0], o[1], o[2], o[3]);
    op[1] = make_float4(o[4], o[5], o[6], o[7]);
}

extern "C" void kernel_launch(void* const* d_in, const int* in_sizes, int n_in,
                              void* d_out, int out_size, void* d_ws, size_t ws_size,
                              hipStream_t stream) {
    const float* query = (const float*)d_in[0];
    const float* value = (const float*)d_in[1];
    const float* rm    = (const float*)d_in[2];
    char* ws = (char*)d_ws;
    double*    rmn    = (double*)ws;
    int*       h_ws   = (int*)(ws + ((size_t)1 << 20));
    int*       hi_ws  = (int*)(ws + ((size_t)2 << 20));
    int*       oi_ws  = (int*)(ws + ((size_t)3 << 20));
    float*     lse_ws = (float*)(ws + ((size_t)4 << 20));
    float*     rwmax  = (float*)(ws + ((size_t)5 << 20));
    float*     rwsum  = (float*)(ws + ((size_t)5 << 20) + 256);
    int*       fix_cnt= (int*)(ws + ((size_t)5 << 20) + 512);
    int*       fix_list=(int*)(ws + ((size_t)5 << 20) + 1024);
    _Float16*  attn_ws= (_Float16*)(ws + ((size_t)6 << 20));
    _Float16*  rhi_g  = (_Float16*)(ws + ((size_t)40 << 20));
    _Float16*  rlo_g  = (_Float16*)(ws + ((size_t)41 << 20));
    int4*      meta_ws= (int4*)(ws + ((size_t)44 << 20));
    float*     out    = (float*)d_out;

    hipLaunchKernelGGL(k_rmnorm, dim3(2048), dim3(64),  0, stream, rm, rmn, rhi_g, rlo_g, fix_cnt);
    hipLaunchKernelGGL(k_hash,   dim3(1024), dim3(256), 0, stream, query, rhi_g, rlo_g,
                       h_ws, fix_cnt, fix_list);
    hipLaunchKernelGGL(k_fix,    dim3(64),   dim3(64),  0, stream, query, rmn,
                       fix_cnt, fix_list, h_ws);
    hipLaunchKernelGGL(k_sort,   dim3(64),   dim3(64),  0, stream, h_ws, hi_ws, oi_ws);
    hipLaunchKernelGGL(k_meta,   dim3(1024), dim3(256), 0, stream, h_ws, hi_ws, oi_ws, meta_ws);
    hipLaunchKernelGGL(k_attn,   dim3(4096), dim3(256), 0, stream,
                       query, value, meta_ws, lse_ws, attn_ws);
    hipLaunchKernelGGL(k_rw,     dim3(64),   dim3(256), 0, stream, lse_ws, rwmax, rwsum);
    hipLaunchKernelGGL(k_out,    dim3(2048), dim3(256), 0, stream,
                       attn_ws, lse_ws, rwmax, rwsum, out);
}

// Round 8
// 167.620 us; speedup vs baseline: 4.2992x; 1.0495x over previous
//
#include <hip/hip_runtime.h>
#include <math.h>

#define B_  16
#define L_  4096
#define D_  64
#define R_  4
#define NB_ 64
#define BL_ 64
#define FIXCAP 8192

typedef _Float16 f16x8 __attribute__((ext_vector_type(8)));
typedef _Float16 f16x2 __attribute__((ext_vector_type(2)));
typedef float    f32x4 __attribute__((ext_vector_type(4)));

// ---------------- ws layout ----------------
// [0MB,1MB)     rmn    double   [B][R][32][64]
// [1MB,2MB)     h      int      [B][R][L]
// [2MB,3MB)     hi     int      [B][R][L]
// [3MB,4MB)     oi     int      [B][R][L]
// [4MB,5MB)     lse    float    [B][R][L]   (original index)
// [5MB,+256)    rwmax float[64]; [+256,+512) rwsum; [+512] fix_cnt; [+1024,) fix_list
// [6MB,40MB)    attn   _Float16 [B][R][L][64]  (original index)
// [40MB,+256K)  rhi    _Float16 [B][128][64]
// [40.5MB,+256K)rlo    _Float16 [B][128][64]
// [41MB,45MB)   meta   int4     [B*R][L]
// [45MB,53MB)   qhf    _Float16 [B][L][64]   raw q, f16
// [53MB,61MB)   khf    _Float16 [B][L][64]   q/||q||/8, f16
// [61MB,69MB)   vhf    _Float16 [B][L][64]   v, f16

// K0: normalize rand_matrix along d, store fp64 + split-f16 copies; zero fix_cnt.
__global__ __launch_bounds__(64) void k_rmnorm(const float* __restrict__ rm,
                                               double* __restrict__ rmn,
                                               _Float16* __restrict__ rhi_g,
                                               _Float16* __restrict__ rlo_g,
                                               int* __restrict__ fix_cnt) {
    if (blockIdx.x == 0 && threadIdx.x == 0) *fix_cnt = 0;
    int blk = blockIdx.x;                 // b*128 + r*32 + n
    int b = blk >> 7, r = (blk >> 5) & 3, n = blk & 31;
    int d = threadIdx.x;
    double v = (double)rm[(((size_t)b * 64 + d) * 4 + r) * 32 + n];
    double sq = v * v;
    #pragma unroll
    for (int off = 32; off > 0; off >>= 1) sq += __shfl_down(sq, off);
    double tot = __shfl(sq, 0);
    double nv = v / sqrt(tot);
    rmn[(((size_t)b * 4 + r) * 32 + n) * 64 + d] = nv;
    float f = (float)nv;
    _Float16 hi = (_Float16)f;
    size_t gi = ((size_t)b * 128 + r * 32 + n) * 64 + d;
    rhi_g[gi] = hi;
    rlo_g[gi] = (_Float16)(f - (float)hi);
}

// K1: split-f16 MFMA hash + f16 tensor prep (qhf/khf/vhf); deferred exact fix list.
__global__ __launch_bounds__(256, 4) void k_hash(const float* __restrict__ q,
                                                 const float* __restrict__ value,
                                                 const _Float16* __restrict__ rhi_g,
                                                 const _Float16* __restrict__ rlo_g,
                                                 int* __restrict__ h_ws,
                                                 int* __restrict__ fix_cnt,
                                                 int* __restrict__ fix_list,
                                                 _Float16* __restrict__ qhf,
                                                 _Float16* __restrict__ khf,
                                                 _Float16* __restrict__ vhf) {
    __shared__ __align__(16) char smem[36864];
    _Float16* Rhi = (_Float16*)smem;            // [128][72]
    _Float16* Rlo = (_Float16*)(smem + 18432);  // [128][72]
    float*    Sc  = (float*)smem;               // overlay [64][133]

    int blk = blockIdx.x;                 // b*64 + chunk
    int b = blk >> 6, chunk = blk & 63;
    int tid = threadIdx.x;
    int w = tid >> 6, lane = tid & 63, quad = lane >> 4, l15 = lane & 15;

    {   // vhf prep: 64 rows of v -> f16 (streaming, no LDS)
        int row = chunk * 64 + (tid >> 2), sub = tid & 3;
        const float4* vp = (const float4*)(value + ((size_t)(b * L_ + row)) * 64 + sub * 16);
        f16x8 h0, h1;
        #pragma unroll
        for (int c = 0; c < 2; c++) {
            float4 t0 = vp[2 * c], t1 = vp[2 * c + 1];
            f16x8& hd = c ? h1 : h0;
            hd[0]=(_Float16)t0.x; hd[1]=(_Float16)t0.y; hd[2]=(_Float16)t0.z; hd[3]=(_Float16)t0.w;
            hd[4]=(_Float16)t1.x; hd[5]=(_Float16)t1.y; hd[6]=(_Float16)t1.z; hd[7]=(_Float16)t1.w;
        }
        _Float16* dst = vhf + ((size_t)(b * L_ + row)) * 64 + sub * 16;
        *(f16x8*)dst = h0;
        *(f16x8*)(dst + 8) = h1;
    }

    {   // stage R split halves
        int row = tid >> 1, dh = (tid & 1) * 32;
        const _Float16* sh = rhi_g + ((size_t)b * 128 + row) * 64 + dh;
        const _Float16* sl = rlo_g + ((size_t)b * 128 + row) * 64 + dh;
        #pragma unroll
        for (int g = 0; g < 4; g++) {
            *(f16x8*)&Rhi[row * 72 + dh + g * 8] = *(const f16x8*)(sh + g * 8);
            *(f16x8*)&Rlo[row * 72 + dh + g * 8] = *(const f16x8*)(sl + g * 8);
        }
    }

    int qrow = chunk * 64 + w * 16 + l15;
    const float* qp = q + ((size_t)(b * L_ + qrow)) * 64;
    float qv[16];
    #pragma unroll
    for (int kt = 0; kt < 2; kt++) {
        float4 t0 = *(const float4*)(qp + kt * 32 + quad * 8);
        float4 t1 = *(const float4*)(qp + kt * 32 + quad * 8 + 4);
        qv[8*kt+0]=t0.x; qv[8*kt+1]=t0.y; qv[8*kt+2]=t0.z; qv[8*kt+3]=t0.w;
        qv[8*kt+4]=t1.x; qv[8*kt+5]=t1.y; qv[8*kt+6]=t1.z; qv[8*kt+7]=t1.w;
    }
    f16x8 Ahi[2], Alo[2];
    #pragma unroll
    for (int kt = 0; kt < 2; kt++) {
        #pragma unroll
        for (int j = 0; j < 8; j++) {
            _Float16 hi = (_Float16)qv[8*kt+j];
            Ahi[kt][j] = hi;
            Alo[kt][j] = (_Float16)(qv[8*kt+j] - (float)hi);
        }
    }
    {   // qhf (raw f16) + khf (scaled f16)
        float ss = 0.f;
        #pragma unroll
        for (int j = 0; j < 16; j++) ss += qv[j] * qv[j];
        ss += __shfl_xor(ss, 16);
        ss += __shfl_xor(ss, 32);
        float nr = sqrtf(ss); if (nr < 1e-12f) nr = 1e-12f;
        float kscale = 0.125f / nr;
        _Float16* qd = qhf + ((size_t)(b * L_ + qrow)) * 64;
        _Float16* kd = khf + ((size_t)(b * L_ + qrow)) * 64;
        #pragma unroll
        for (int kt = 0; kt < 2; kt++) {
            *(f16x8*)(qd + kt * 32 + quad * 8) = Ahi[kt];
            f16x8 hv;
            #pragma unroll
            for (int j = 0; j < 8; j++) hv[j] = (_Float16)(qv[8*kt+j] * kscale);
            *(f16x8*)(kd + kt * 32 + quad * 8) = hv;
        }
    }
    __syncthreads();

    f32x4 acc[8];
    #pragma unroll
    for (int jt = 0; jt < 8; jt++) acc[jt] = (f32x4){0.f, 0.f, 0.f, 0.f};
    #pragma unroll
    for (int jt = 0; jt < 8; jt++) {
        #pragma unroll
        for (int kt = 0; kt < 2; kt++) {
            f16x8 bh = *(const f16x8*)&Rhi[(jt * 16 + l15) * 72 + kt * 32 + quad * 8];
            f16x8 bl = *(const f16x8*)&Rlo[(jt * 16 + l15) * 72 + kt * 32 + quad * 8];
            acc[jt] = __builtin_amdgcn_mfma_f32_16x16x32_f16(Ahi[kt], bh, acc[jt], 0, 0, 0);
            acc[jt] = __builtin_amdgcn_mfma_f32_16x16x32_f16(Ahi[kt], bl, acc[jt], 0, 0, 0);
            acc[jt] = __builtin_amdgcn_mfma_f32_16x16x32_f16(Alo[kt], bh, acc[jt], 0, 0, 0);
        }
    }
    __syncthreads();

    #pragma unroll
    for (int jt = 0; jt < 8; jt++) {
        #pragma unroll
        for (int reg = 0; reg < 4; reg++)
            Sc[(w * 16 + quad * 4 + reg) * 133 + jt * 16 + l15] = acc[jt][reg];
    }
    __syncthreads();

    {
        int row = tid & 63, r = tid >> 6;
        const float* sp = &Sc[row * 133 + r * 32];
        float bp = -1e30f, bn = -1e30f; int ip = 0, in2 = 0;
        float v1 = -1e30f, v2 = -1e30f;
        #pragma unroll
        for (int n = 0; n < 32; n++) {
            float v = sp[n], nv = -v;
            if (v > bp)  { bp = v;  ip = n; }
            if (nv > bn) { bn = nv; in2 = n; }
            if (v > v1)       { v2 = v1; v1 = v; }
            else if (v > v2)  { v2 = v; }
            if (nv > v1)      { v2 = v1; v1 = nv; }
            else if (nv > v2) { v2 = nv; }
        }
        int i1 = (bp >= bn) ? ip : (32 + in2);
        int l = chunk * 64 + row;
        h_ws[((size_t)(b * 4 + r)) * L_ + l] = i1;
        if (v1 - v2 < 4e-5f) {
            int slot = atomicAdd(fix_cnt, 1);
            if (slot < FIXCAP) fix_list[slot] = (b << 14) | (r << 12) | l;
        }
    }
}

// K1b: exact fp64 resolve, one wave per flagged row.
__global__ __launch_bounds__(64) void k_fix(const float* __restrict__ q,
                                            const double* __restrict__ rmn,
                                            const int* __restrict__ fix_cnt,
                                            const int* __restrict__ fix_list,
                                            int* __restrict__ h_ws) {
    int cnt = *fix_cnt; if (cnt > FIXCAP) cnt = FIXCAP;
    int lane = threadIdx.x;
    for (int i = blockIdx.x; i < cnt; i += gridDim.x) {
        int e = fix_list[i];
        int b = e >> 14, r = (e >> 12) & 3, l = e & 4095;
        int n = lane & 31;
        const double* rp = rmn + ((size_t)(b * 4 + r)) * 2048 + n * 64;
        const float* qr = q + ((size_t)(b * L_ + l)) * 64;
        double a0 = 0.0, a1 = 0.0, a2 = 0.0, a3 = 0.0;
        #pragma unroll
        for (int d = 0; d < 64; d += 4) {
            a0 += (double)qr[d]   * rp[d];
            a1 += (double)qr[d+1] * rp[d+1];
            a2 += (double)qr[d+2] * rp[d+2];
            a3 += (double)qr[d+3] * rp[d+3];
        }
        double acc = ((a0 + a1) + (a2 + a3));
        double v = (lane < 32) ? acc : -acc;
        int idx = lane;
        #pragma unroll
        for (int off = 1; off < 64; off <<= 1) {
            double ov = __shfl_xor(v, off);
            int   oidx = __shfl_xor(idx, off);
            if (ov > v || (ov == v && oidx < idx)) { v = ov; idx = oidx; }
        }
        if (lane == 0) h_ws[((size_t)(b * 4 + r)) * L_ + l] = idx;
    }
}

// K2: stable counting sort per (b,r)
__global__ __launch_bounds__(64) void k_sort(const int* __restrict__ h_ws,
                                             int* __restrict__ hi_ws,
                                             int* __restrict__ oi_ws) {
    __shared__ int hs[64 * 65];
    __shared__ int cnt[64 * 65];
    int br = blockIdx.x;
    const int* hp = h_ws + (size_t)br * L_;
    int t = threadIdx.x;
    for (int w = 0; w < 64; w++) hs[w * 65 + t] = hp[w * 64 + t];
    for (int u = 0; u < 64; u++) cnt[t * 65 + u] = 0;
    __syncthreads();
    for (int k = 0; k < 64; k++) cnt[t * 65 + hs[t * 65 + k]]++;
    __syncthreads();
    int cs = 0;
    for (int c = 0; c < 64; c++) cs += cnt[c * 65 + t];
    int v = cs;
    #pragma unroll
    for (int off = 1; off < 64; off <<= 1) {
        int u = __shfl_up(v, off);
        if (t >= off) v += u;
    }
    int running = v - cs;
    for (int c = 0; c < 64; c++) {
        int tmp = cnt[c * 65 + t];
        cnt[c * 65 + t] = running;
        running += tmp;
    }
    __syncthreads();
    int* hi = hi_ws + (size_t)br * L_;
    int* oi = oi_ws + (size_t)br * L_;
    for (int k = 0; k < 64; k++) {
        int idx = t * 64 + k;
        int b2 = hs[t * 65 + k];
        int pos = cnt[t * 65 + b2]++;
        hi[pos] = idx;
        oi[idx] = pos;
    }
}

// K2b: per sorted position meta record
__global__ __launch_bounds__(256) void k_meta(const int* __restrict__ h_ws,
                                              const int* __restrict__ hi_ws,
                                              const int* __restrict__ oi_ws,
                                              int4* __restrict__ meta_ws) {
    int gid = blockIdx.x * 256 + threadIdx.x;
    int br = gid >> 12, spos = gid & 4095;
    int b = br >> 2;
    int p = hi_ws[(size_t)br * L_ + spos];
    int hh = h_ws[(size_t)br * L_ + p];
    int pack = 0, packm1 = 0;
    #pragma unroll
    for (int r2 = 0; r2 < 4; r2++) {
        int bk = oi_ws[((size_t)(b * 4 + r2)) * L_ + p] >> 6;
        pack   |= bk << (8 * r2);
        packm1 |= ((bk + 63) & 63) << (8 * r2);
    }
    meta_ws[(size_t)br * L_ + spos] = make_int4(hh, p, pack, packm1);
}

// K3: MFMA fused attention; all staging = gathered f16 copies; rcp instead of div.
__global__ __launch_bounds__(256, 4) void k_attn(const _Float16* __restrict__ qhf,
                                                 const _Float16* __restrict__ khf,
                                                 const _Float16* __restrict__ vhf,
                                                 const int4* __restrict__ meta_ws,
                                                 float* __restrict__ lse_ws,
                                                 _Float16* __restrict__ attn_ws) {
    __shared__ _Float16 Ksh[128 * 72];    // 18432 B; overlaid by Ph[64][136]
    __shared__ _Float16 Vt[64 * 136];     // 17408 B
    __shared__ int4 kmeta[128];

    int xcd = blockIdx.x & 7, slot = blockIdx.x >> 3;
    int b = xcd * 2 + (slot >> 8);
    int rem = slot & 255, n = rem >> 2, r = rem & 3;
    int tid = threadIdx.x;
    int w = tid >> 6, lane = tid & 63, quad = lane >> 4, l15 = lane & 15;
    int hibase = (b * 4 + r) * L_;

    if (tid < 128) {
        int j = tid;
        int nprev = (n + 63) & 63;
        int spos = (j < 64) ? (nprev * 64 + j) : (n * 64 + (j - 64));
        kmeta[j] = meta_ws[hibase + spos];
    }
    __syncthreads();

    {   // stage K: pure gathered f16 copy, 2 threads per row
        int j = tid >> 1, dh = (tid & 1) * 32;
        const _Float16* src = khf + ((size_t)(b * L_ + kmeta[j].y)) * 64 + dh;
        #pragma unroll
        for (int g = 0; g < 4; g++)
            *(f16x8*)&Ksh[j * 72 + dh + g * 8] = *(const f16x8*)(src + g * 8);
    }
    {   // stage V^T: thread = (row-pair m, d-quarter sub)
        int m = tid >> 2, sub = tid & 3;
        const _Float16* v0 = vhf + ((size_t)(b * L_ + kmeta[2 * m].y)) * 64 + sub * 16;
        const _Float16* v1 = vhf + ((size_t)(b * L_ + kmeta[2 * m + 1].y)) * 64 + sub * 16;
        f16x8 a00 = *(const f16x8*)v0, a01 = *(const f16x8*)(v0 + 8);
        f16x8 a10 = *(const f16x8*)v1, a11 = *(const f16x8*)(v1 + 8);
        #pragma unroll
        for (int d = 0; d < 8; d++) {
            f16x2 hv = { a00[d], a10[d] };
            *(f16x2*)&Vt[(sub * 16 + d) * 136 + 2 * m] = hv;
            f16x2 hw = { a01[d], a11[d] };
            *(f16x2*)&Vt[(sub * 16 + 8 + d) * 136 + 2 * m] = hw;
        }
    }

    // Q A-frags direct from qhf (gathered 16B loads)
    int4 qmw = kmeta[64 + w * 16 + l15];
    const _Float16* qp = qhf + ((size_t)(b * L_ + qmw.y)) * 64;
    f16x8 afr[2];
    afr[0] = *(const f16x8*)(qp + quad * 8);
    afr[1] = *(const f16x8*)(qp + 32 + quad * 8);
    __syncthreads();

    f32x4 acc[8];
    #pragma unroll
    for (int jt = 0; jt < 8; jt++) acc[jt] = (f32x4){0.f, 0.f, 0.f, 0.f};
    #pragma unroll
    for (int jt = 0; jt < 8; jt++) {
        #pragma unroll
        for (int kt = 0; kt < 2; kt++) {
            f16x8 bfr = *(const f16x8*)&Ksh[(jt * 16 + l15) * 72 + kt * 32 + quad * 8];
            acc[jt] = __builtin_amdgcn_mfma_f32_16x16x32_f16(afr[kt], bfr, acc[jt], 0, 0, 0);
        }
    }

    int4 qm4[4], km4[8];
    #pragma unroll
    for (int reg = 0; reg < 4; reg++) qm4[reg] = kmeta[64 + w * 16 + quad * 4 + reg];
    #pragma unroll
    for (int jt = 0; jt < 8; jt++) km4[jt] = kmeta[jt * 16 + l15];
    __syncthreads();                      // QK reads of Ksh done -> overlay

    _Float16* Ph = Ksh;
    float lse_r[4];
    #pragma unroll
    for (int reg = 0; reg < 4; reg++) {
        float s[8];
        #pragma unroll
        for (int jt = 0; jt < 8; jt++) {
            float v = acc[jt][reg];
            if (km4[jt].x != qm4[reg].x) v = -1e9f;
            if (qm4[reg].y < km4[jt].y)  v = -1e9f;
            if (qm4[reg].y == km4[jt].y) v = -1e5f;
            s[jt] = v;
        }
        float m = s[0];
        #pragma unroll
        for (int jt = 1; jt < 8; jt++) m = fmaxf(m, s[jt]);
        #pragma unroll
        for (int off = 1; off < 16; off <<= 1) m = fmaxf(m, __shfl_xor(m, off));
        float te[8], sum = 0.f;
        #pragma unroll
        for (int jt = 0; jt < 8; jt++) { te[jt] = __expf(s[jt] - m); sum += te[jt]; }
        #pragma unroll
        for (int off = 1; off < 16; off <<= 1) sum += __shfl_xor(sum, off);
        float inv = __builtin_amdgcn_rcpf(sum);
        lse_r[reg] = m + __logf(sum);
        int i = w * 16 + quad * 4 + reg;
        #pragma unroll
        for (int jt = 0; jt < 8; jt++) {
            int z1 = km4[jt].z ^ qm4[reg].z;
            int z2 = km4[jt].z ^ qm4[reg].w;
            int nz = __popc((z1 + 0x7f7f7f7f) & 0x80808080)
                   + __popc((z2 + 0x7f7f7f7f) & 0x80808080);
            float p = te[jt] * inv * __builtin_amdgcn_rcpf((float)(8 - nz));
            Ph[i * 136 + jt * 16 + l15] = (_Float16)p;
        }
    }
    if (l15 == 0) {
        #pragma unroll
        for (int reg = 0; reg < 4; reg++)
            lse_ws[hibase + qm4[reg].y] = lse_r[reg];
    }
    __syncthreads();

    f32x4 oacc[4];
    #pragma unroll
    for (int nt = 0; nt < 4; nt++) oacc[nt] = (f32x4){0.f, 0.f, 0.f, 0.f};
    #pragma unroll
    for (int kt = 0; kt < 4; kt++) {
        f16x8 pa = *(const f16x8*)&Ph[(w * 16 + l15) * 136 + kt * 32 + quad * 8];
        #pragma unroll
        for (int nt = 0; nt < 4; nt++) {
            f16x8 vb = *(const f16x8*)&Vt[(nt * 16 + l15) * 136 + kt * 32 + quad * 8];
            oacc[nt] = __builtin_amdgcn_mfma_f32_16x16x32_f16(pa, vb, oacc[nt], 0, 0, 0);
        }
    }
    #pragma unroll
    for (int reg = 0; reg < 4; reg++) {
        size_t base = (((size_t)(b * 4 + r)) * L_ + qm4[reg].y) * 64;
        #pragma unroll
        for (int nt = 0; nt < 4; nt++)
            attn_ws[base + nt * 16 + l15] = (_Float16)oacc[nt][reg];
    }
}

// K4a: per (b,r) softmax-over-L stats of lse
__global__ __launch_bounds__(256) void k_rw(const float* __restrict__ lse_ws,
                                            float* __restrict__ rwmax,
                                            float* __restrict__ rwsum) {
    __shared__ float  red[256];
    __shared__ double redd[256];
    int br = blockIdx.x;
    const float* lp = lse_ws + (size_t)br * L_;
    int t = threadIdx.x;
    float m = -1e30f;
    for (int k = t; k < L_; k += 256) m = fmaxf(m, lp[k]);
    red[t] = m; __syncthreads();
    for (int s2 = 128; s2 > 0; s2 >>= 1) {
        if (t < s2) red[t] = fmaxf(red[t], red[t + s2]);
        __syncthreads();
    }
    float mm = red[0];
    double s = 0.0;
    for (int k = t; k < L_; k += 256) s += (double)expf(lp[k] - mm);
    redd[t] = s; __syncthreads();
    for (int s2 = 128; s2 > 0; s2 >>= 1) {
        if (t < s2) redd[t] += redd[t + s2];
        __syncthreads();
    }
    if (t == 0) { rwmax[br] = mm; rwsum[br] = (float)redd[0]; }
}

// K4b: vectorized combine — thread = (b,l, d-octet)
__global__ __launch_bounds__(256) void k_out(const _Float16* __restrict__ attn_ws,
                                             const float* __restrict__ lse_ws,
                                             const float* __restrict__ rwmax,
                                             const float* __restrict__ rwsum,
                                             float* __restrict__ out) {
    int gid = blockIdx.x * 256 + threadIdx.x;   // B*L*8
    int g = gid & 7;
    size_t row = (size_t)(gid >> 3);            // b*L + l
    int b = (int)(row >> 12), l = (int)(row & 4095);
    float o[8];
    #pragma unroll
    for (int k = 0; k < 8; k++) o[k] = 0.f;
    #pragma unroll
    for (int r = 0; r < 4; r++) {
        int br = b * 4 + r;
        float wgt = __expf(lse_ws[(size_t)br * L_ + l] - rwmax[br])
                  * __builtin_amdgcn_rcpf(rwsum[br]);
        f16x8 av = *(const f16x8*)&attn_ws[(((size_t)br * L_ + l) << 6) + g * 8];
        #pragma unroll
        for (int k = 0; k < 8; k++) o[k] += (float)av[k] * wgt;
    }
    float4* op = (float4*)(out + row * 64 + g * 8);
    op[0] = make_float4(o[0], o[1], o[2], o[3]);
    op[1] = make_float4(o[4], o[5], o[6], o[7]);
}

extern "C" void kernel_launch(void* const* d_in, const int* in_sizes, int n_in,
                              void* d_out, int out_size, void* d_ws, size_t ws_size,
                              hipStream_t stream) {
    const float* query = (const float*)d_in[0];
    const float* value = (const float*)d_in[1];
    const float* rm    = (const float*)d_in[2];
    char* ws = (char*)d_ws;
    double*    rmn    = (double*)ws;
    int*       h_ws   = (int*)(ws + ((size_t)1 << 20));
    int*       hi_ws  = (int*)(ws + ((size_t)2 << 20));
    int*       oi_ws  = (int*)(ws + ((size_t)3 << 20));
    float*     lse_ws = (float*)(ws + ((size_t)4 << 20));
    float*     rwmax  = (float*)(ws + ((size_t)5 << 20));
    float*     rwsum  = (float*)(ws + ((size_t)5 << 20) + 256);
    int*       fix_cnt= (int*)(ws + ((size_t)5 << 20) + 512);
    int*       fix_list=(int*)(ws + ((size_t)5 << 20) + 1024);
    _Float16*  attn_ws= (_Float16*)(ws + ((size_t)6 << 20));
    _Float16*  rhi_g  = (_Float16*)(ws + ((size_t)40 << 20));
    _Float16*  rlo_g  = (_Float16*)(ws + ((size_t)40 << 20) + ((size_t)1 << 19));
    int4*      meta_ws= (int4*)(ws + ((size_t)41 << 20));
    _Float16*  qhf    = (_Float16*)(ws + ((size_t)45 << 20));
    _Float16*  khf    = (_Float16*)(ws + ((size_t)53 << 20));
    _Float16*  vhf    = (_Float16*)(ws + ((size_t)61 << 20));
    float*     out    = (float*)d_out;

    hipLaunchKernelGGL(k_rmnorm, dim3(2048), dim3(64),  0, stream, rm, rmn, rhi_g, rlo_g, fix_cnt);
    hipLaunchKernelGGL(k_hash,   dim3(1024), dim3(256), 0, stream, query, value, rhi_g, rlo_g,
                       h_ws, fix_cnt, fix_list, qhf, khf, vhf);
    hipLaunchKernelGGL(k_fix,    dim3(64),   dim3(64),  0, stream, query, rmn,
                       fix_cnt, fix_list, h_ws);
    hipLaunchKernelGGL(k_sort,   dim3(64),   dim3(64),  0, stream, h_ws, hi_ws, oi_ws);
    hipLaunchKernelGGL(k_meta,   dim3(1024), dim3(256), 0, stream, h_ws, hi_ws, oi_ws, meta_ws);
    hipLaunchKernelGGL(k_attn,   dim3(4096), dim3(256), 0, stream,
                       qhf, khf, vhf, meta_ws, lse_ws, attn_ws);
    hipLaunchKernelGGL(k_rw,     dim3(64),   dim3(256), 0, stream, lse_ws, rwmax, rwsum);
    hipLaunchKernelGGL(k_out,    dim3(2048), dim3(256), 0, stream,
                       attn_ws, lse_ws, rwmax, rwsum, out);
}